// Round 1
// baseline (267.238 us; speedup 1.0000x reference)
//
#include <hip/hip_runtime.h>

typedef unsigned short u16;
typedef unsigned int u32;
typedef __attribute__((ext_vector_type(4))) float f32x4;
typedef __attribute__((ext_vector_type(8))) short bf16x8;
typedef __attribute__((ext_vector_type(4))) unsigned short u16x4;

#define MFMA16x16x32(a, b, c) __builtin_amdgcn_mfma_f32_16x16x32_bf16((a), (b), (c), 0, 0, 0)

static constexpr int M_TOK = 8192;  // B*S = 4*2048

__device__ __forceinline__ u16 f2bf(float f) {
  u32 u = __float_as_uint(f);
  return (u16)((u + 0x7FFFu + ((u >> 16) & 1u)) >> 16);  // RNE
}

__device__ __forceinline__ void gload16(const u16* g, u16* l) {
  // async global->LDS, 16B per lane; LDS dest must be wave-uniform base
  __builtin_amdgcn_global_load_lds(
      (const __attribute__((address_space(1))) u32*)(const void*)g,
      (__attribute__((address_space(3))) u32*)(void*)l, 16, 0, 0);
}

// ---- elementwise fp32 -> bf16 cast (x) ----
__global__ void cast_x_kernel(const float* __restrict__ in, u16* __restrict__ out, int total4) {
  for (int i = blockIdx.x * blockDim.x + threadIdx.x; i < total4; i += gridDim.x * blockDim.x) {
    float4 v = ((const float4*)in)[i];
    u16x4 o;
    o[0] = f2bf(v.x); o[1] = f2bf(v.y); o[2] = f2bf(v.z); o[3] = f2bf(v.w);
    ((u16x4*)out)[i] = o;
  }
}

// ---- per-expert transpose + cast: in [z][P][Q] fp32 -> out [z][Q][P] bf16 ----
__global__ void tcast_kernel(const float* __restrict__ in, u16* __restrict__ out, int P, int Q) {
  __shared__ float tile[32][33];
  const int z = blockIdx.z;
  const int q0 = blockIdx.x * 32, p0 = blockIdx.y * 32;
  const float* src = in + (size_t)z * P * Q;
  u16* dst = out + (size_t)z * P * Q;
  const int tx = threadIdx.x & 31, ty = threadIdx.x >> 5;  // 256 thr: ty 0..7
#pragma unroll
  for (int k = 0; k < 4; ++k)
    tile[ty + k * 8][tx] = src[(size_t)(p0 + ty + k * 8) * Q + q0 + tx];
  __syncthreads();
#pragma unroll
  for (int k = 0; k < 4; ++k)
    dst[(size_t)(q0 + ty + k * 8) * P + p0 + tx] = f2bf(tile[tx][ty + k * 8]);
}

// ---- sum 2 split-K partials, cast to bf16 (h) ----
__global__ void combine_h_kernel(const float* __restrict__ Pp, u16* __restrict__ h, int total4) {
  int i = blockIdx.x * blockDim.x + threadIdx.x;
  if (i >= total4) return;
  float4 a = ((const float4*)Pp)[i];
  float4 b = ((const float4*)Pp)[i + total4];
  u16x4 o;
  o[0] = f2bf(a.x + b.x); o[1] = f2bf(a.y + b.y);
  o[2] = f2bf(a.z + b.z); o[3] = f2bf(a.w + b.w);
  ((u16x4*)h)[i] = o;
}

// ---- grouped GEMM with per-(row, group) weighting folded into accumulator ----
// A   : [M_TOK][Kg] bf16 (same A columns re-used for every group n)
// B   : [16][Ntot][Kg] bf16 (pre-transposed so k is contiguous per output col)
// W   : [M_TOK][16] fp32
// Out : fp32 [M_TOK][Ntot], offset by blockIdx.z*M_TOK*Ntot (split-K partials)
template <int BN, int GROUP_STEPS, int NGPB>
__global__ __launch_bounds__(256, 2) void moe_gemm(
    const u16* __restrict__ A, const u16* __restrict__ B,
    const float* __restrict__ W, float* __restrict__ Out, int Ntot) {
  constexpr int BM = 128, BK = 64;
  constexpr int Kg = GROUP_STEPS * BK;
  constexpr int WN = BN / 2;       // wave tile = 64 x WN (2x2 wave grid)
  constexpr int NJ = WN / 16;
  constexpr int BCW = (BN / 8) / 4;  // B-tile 1KB chunks per wave
  static_assert(BCW >= 1, "");

  __shared__ u16 Alds[BM * BK];
  __shared__ u16 Blds[BN * BK];
  __shared__ float Wlds[BM * 17];

  const int tid = threadIdx.x;
  const int lane = tid & 63;
  const int wid = tid >> 6;
  const int wr = wid >> 1, wc = wid & 1;

  const int m0 = blockIdx.y * BM;
  const int bn0 = blockIdx.x * BN;
  const int group0 = blockIdx.z * NGPB;
  Out += (size_t)blockIdx.z * M_TOK * Ntot;

  for (int i = tid; i < BM * 16; i += 256)
    Wlds[(i >> 4) * 17 + (i & 15)] = W[(size_t)(m0 + (i >> 4)) * 16 + (i & 15)];

  const f32x4 vzero = {0.f, 0.f, 0.f, 0.f};
  f32x4 acc_t[4][NJ], acc_g[4][NJ];
#pragma unroll
  for (int mi = 0; mi < 4; ++mi)
#pragma unroll
    for (int nj = 0; nj < NJ; ++nj) { acc_t[mi][nj] = vzero; acc_g[mi][nj] = vzero; }

  const int lrow = lane >> 3;        // row within an 8-row/1KB staging chunk
  const int lcol = (lane & 7) * 8;   // bf16 col within BK=64
  const u16* Arow0 = A + (size_t)m0 * Kg;

  for (int g = 0; g < NGPB; ++g) {
    const int n = group0 + g;
    const u16* Brow0 = B + ((size_t)n * Ntot + bn0) * Kg;
    for (int t = 0; t < GROUP_STEPS; ++t) {
      const int k0 = t * BK;
      // stage A tile [128][64] linearly (row-major), 16 chunks of 1KB
#pragma unroll
      for (int c = 0; c < 4; ++c) {
        const int chunk = wid * 4 + c;
        gload16(Arow0 + (size_t)(chunk * 8 + lrow) * Kg + k0 + lcol, &Alds[chunk * 512]);
      }
      // stage B tile [BN][64]
#pragma unroll
      for (int c = 0; c < BCW; ++c) {
        const int chunk = wid * BCW + c;
        gload16(Brow0 + (size_t)(chunk * 8 + lrow) * Kg + k0 + lcol, &Blds[chunk * 512]);
      }
      __syncthreads();  // drains vmcnt before barrier -> LDS valid
#pragma unroll
      for (int kk = 0; kk < 2; ++kk) {
        bf16x8 av[4], bv[NJ];
        const int koff = kk * 32 + (lane >> 4) * 8;
#pragma unroll
        for (int mi = 0; mi < 4; ++mi)
          av[mi] = *(const bf16x8*)&Alds[(wr * 64 + mi * 16 + (lane & 15)) * 64 + koff];
#pragma unroll
        for (int nj = 0; nj < NJ; ++nj)
          bv[nj] = *(const bf16x8*)&Blds[(wc * WN + nj * 16 + (lane & 15)) * 64 + koff];
#pragma unroll
        for (int mi = 0; mi < 4; ++mi)
#pragma unroll
          for (int nj = 0; nj < NJ; ++nj)
            acc_g[mi][nj] = MFMA16x16x32(av[mi], bv[nj], acc_g[mi][nj]);
      }
      __syncthreads();  // protect LDS before next stage overwrites
    }
    // fold group accumulator: acc_t += w[row, n] * acc_g  (C/D row = (lane>>4)*4+reg)
#pragma unroll
    for (int mi = 0; mi < 4; ++mi) {
      const int rbase = wr * 64 + mi * 16 + (lane >> 4) * 4;
      const float w0 = Wlds[(rbase + 0) * 17 + n];
      const float w1 = Wlds[(rbase + 1) * 17 + n];
      const float w2 = Wlds[(rbase + 2) * 17 + n];
      const float w3 = Wlds[(rbase + 3) * 17 + n];
#pragma unroll
      for (int nj = 0; nj < NJ; ++nj) {
        acc_t[mi][nj][0] += w0 * acc_g[mi][nj][0];
        acc_t[mi][nj][1] += w1 * acc_g[mi][nj][1];
        acc_t[mi][nj][2] += w2 * acc_g[mi][nj][2];
        acc_t[mi][nj][3] += w3 * acc_g[mi][nj][3];
        acc_g[mi][nj] = vzero;
      }
    }
  }
  // epilogue: fp32 store, col = lane&15 (verified C/D layout)
#pragma unroll
  for (int mi = 0; mi < 4; ++mi) {
    const int rbase = wr * 64 + mi * 16 + (lane >> 4) * 4;
#pragma unroll
    for (int j = 0; j < 4; ++j) {
      float* orow = Out + (size_t)(m0 + rbase + j) * Ntot + bn0 + wc * WN + (lane & 15);
#pragma unroll
      for (int nj = 0; nj < NJ; ++nj) orow[nj * 16] = acc_t[mi][nj][j];
    }
  }
}

extern "C" void kernel_launch(void* const* d_in, const int* in_sizes, int n_in,
                              void* d_out, int out_size, void* d_ws, size_t ws_size,
                              hipStream_t stream) {
  const float* x  = (const float*)d_in[0];   // [8192][1024]
  const float* F  = (const float*)d_in[1];   // [16][1024][256]
  const float* Rk = (const float*)d_in[2];   // [16][256][1024]
  const float* Wf = (const float*)d_in[3];   // [8192][16]
  const float* Wr = (const float*)d_in[4];   // [8192][16]
  float* out = (float*)d_out;                // [8192][1024]

  char* ws = (char*)d_ws;
  u16*   X16 = (u16*)(ws);                    // 16,777,216 B  x bf16 [8192][1024]
  u16*   Ft  = (u16*)(ws + 16777216);         //  8,388,608 B  F^T  [16][256][1024]
  u16*   Rt  = (u16*)(ws + 25165824);         //  8,388,608 B  Rk^T [16][1024][256]
  u16*   h16 = (u16*)(ws + 33554432);         //  4,194,304 B  h bf16 [8192][256]
  float* Pp  = (float*)(ws + 37748736);       // 16,777,216 B  partials [2][8192][256]
  // total 54,525,952 B of d_ws used

  // 1) casts / transposes
  cast_x_kernel<<<2048, 256, 0, stream>>>(x, X16, (M_TOK * 1024) / 4);
  tcast_kernel<<<dim3(8, 32, 16), 256, 0, stream>>>(F, Ft, 1024, 256);   // [n][d][r] -> [n][r][d]
  tcast_kernel<<<dim3(32, 8, 16), 256, 0, stream>>>(Rk, Rt, 256, 1024);  // [n][r][d] -> [n][d][r]

  // 2) stage 1: h_partial[z][m][r] = sum_{n in z-half} wf[m,n] * (x[m,:] @ F[n])
  //    BM=128 BN=64, K=8*1024 per block, grid 4*64*2 = 512 blocks
  moe_gemm<64, 16, 8><<<dim3(4, 64, 2), 256, 0, stream>>>(X16, Ft, Wf, Pp, 256);

  // 3) combine partials -> h bf16
  combine_h_kernel<<<2048, 256, 0, stream>>>(Pp, h16, (M_TOK * 256) / 4);

  // 4) stage 2: out[m][d] = sum_n wr[m,n] * (h[m,:] @ Rk[n]) ; grid 8*64 = 512 blocks
  moe_gemm<128, 4, 16><<<dim3(8, 64, 1), 256, 0, stream>>>(h16, Rt, Wr, out, 1024);
}

// Round 2
// 243.006 us; speedup vs baseline: 1.0997x; 1.0997x over previous
//
#include <hip/hip_runtime.h>

typedef unsigned short u16;
typedef unsigned int u32;
typedef __attribute__((ext_vector_type(4))) float f32x4;
typedef __attribute__((ext_vector_type(8))) short bf16x8;
typedef __attribute__((ext_vector_type(4))) unsigned short u16x4;

#define MFMA16x16x32(a, b, c) __builtin_amdgcn_mfma_f32_16x16x32_bf16((a), (b), (c), 0, 0, 0)

static constexpr int M_TOK = 8192;  // B*S

__device__ __forceinline__ u16 f2bf(float f) {
  u32 u = __float_as_uint(f);
  return (u16)((u + 0x7FFFu + ((u >> 16) & 1u)) >> 16);  // RNE
}
__device__ __forceinline__ float bf2f(u16 b) {
  u32 u = ((u32)b) << 16;
  return __uint_as_float(u);
}

__device__ __forceinline__ void gload16(const u16* g, u16* l) {
  __builtin_amdgcn_global_load_lds(
      (const __attribute__((address_space(1))) u32*)(const void*)g,
      (__attribute__((address_space(3))) u32*)(void*)l, 16, 0, 0);
}

// ---- elementwise fp32 -> bf16 cast ----
__global__ void cast_x_kernel(const float* __restrict__ in, u16* __restrict__ out, int total4) {
  for (int i = blockIdx.x * blockDim.x + threadIdx.x; i < total4; i += gridDim.x * blockDim.x) {
    float4 v = ((const float4*)in)[i];
    u16x4 o;
    o[0] = f2bf(v.x); o[1] = f2bf(v.y); o[2] = f2bf(v.z); o[3] = f2bf(v.w);
    ((u16x4*)out)[i] = o;
  }
}

// ---- transpose + cast: in [z][P][Q] fp32 -> out [z][Q][P] bf16 ----
__global__ void tcast_kernel(const float* __restrict__ in, u16* __restrict__ out, int P, int Q) {
  __shared__ float tile[32][33];
  const int z = blockIdx.z;
  const int q0 = blockIdx.x * 32, p0 = blockIdx.y * 32;
  const float* src = in + (size_t)z * P * Q;
  u16* dst = out + (size_t)z * P * Q;
  const int tx = threadIdx.x & 31, ty = threadIdx.x >> 5;
#pragma unroll
  for (int k = 0; k < 4; ++k)
    tile[ty + k * 8][tx] = src[(size_t)(p0 + ty + k * 8) * Q + q0 + tx];
  __syncthreads();
#pragma unroll
  for (int k = 0; k < 4; ++k)
    dst[(size_t)(q0 + ty + k * 8) * P + p0 + tx] = f2bf(tile[tx][ty + k * 8]);
}

// ---- standard GEMM, m97 structure: BM=BN=128, BK=64, 4 waves (2x2), gload_lds w=16 ----
// A: [M][K] bf16, B: [N][K] bf16 (k contiguous per output col). Out: [M][N].
template <int KSTEPS, bool OUT_BF16>
__global__ __launch_bounds__(256) void gemm_bt(
    const u16* __restrict__ A, const u16* __restrict__ B, void* __restrict__ OutV,
    int N, int K) {
  __shared__ u16 Alds[128 * 64];
  __shared__ u16 Blds[128 * 64];

  const int tid = threadIdx.x;
  const int lane = tid & 63;
  const int wid = tid >> 6;
  const int wr = wid >> 1, wc = wid & 1;

  // XCD-aware bijective swizzle (nwg % 8 == 0 for all our grids)
  const int nwg = gridDim.x * gridDim.y;
  int wgid = blockIdx.y * gridDim.x + blockIdx.x;
  wgid = (wgid & 7) * (nwg >> 3) + (wgid >> 3);
  const int by = wgid / gridDim.x, bx = wgid - by * gridDim.x;

  const int m0 = by * 128;
  const int bn0 = bx * 128;

  const f32x4 vzero = {0.f, 0.f, 0.f, 0.f};
  f32x4 acc[4][4];
#pragma unroll
  for (int mi = 0; mi < 4; ++mi)
#pragma unroll
    for (int nj = 0; nj < 4; ++nj) acc[mi][nj] = vzero;

  const int lrow = lane >> 3;        // 0..7 row within 8-row/1KB chunk
  const int lcol = (lane & 7) * 8;   // bf16 col within BK=64
  const u16* Arow0 = A + (size_t)m0 * K;
  const u16* Brow0 = B + (size_t)bn0 * K;

  for (int t = 0; t < KSTEPS; ++t) {
    const int k0 = t * 64;
#pragma unroll
    for (int c = 0; c < 4; ++c) {
      const int chunk = wid * 4 + c;
      gload16(Arow0 + (size_t)(chunk * 8 + lrow) * K + k0 + lcol, &Alds[chunk * 512]);
      gload16(Brow0 + (size_t)(chunk * 8 + lrow) * K + k0 + lcol, &Blds[chunk * 512]);
    }
    __syncthreads();
#pragma unroll
    for (int kk = 0; kk < 2; ++kk) {
      bf16x8 av[4], bv[4];
      const int koff = kk * 32 + (lane >> 4) * 8;
#pragma unroll
      for (int mi = 0; mi < 4; ++mi)
        av[mi] = *(const bf16x8*)&Alds[(wr * 64 + mi * 16 + (lane & 15)) * 64 + koff];
#pragma unroll
      for (int nj = 0; nj < 4; ++nj)
        bv[nj] = *(const bf16x8*)&Blds[(wc * 64 + nj * 16 + (lane & 15)) * 64 + koff];
#pragma unroll
      for (int mi = 0; mi < 4; ++mi)
#pragma unroll
        for (int nj = 0; nj < 4; ++nj)
          acc[mi][nj] = MFMA16x16x32(av[mi], bv[nj], acc[mi][nj]);
    }
    __syncthreads();
  }

  // epilogue: C/D row = (lane>>4)*4 + j, col = lane&15 (verified layout)
#pragma unroll
  for (int mi = 0; mi < 4; ++mi) {
    const int rbase = wr * 64 + mi * 16 + (lane >> 4) * 4;
#pragma unroll
    for (int j = 0; j < 4; ++j) {
      const size_t row = m0 + rbase + j;
      if constexpr (OUT_BF16) {
        u16* orow = (u16*)OutV + row * N + bn0 + wc * 64 + (lane & 15);
#pragma unroll
        for (int nj = 0; nj < 4; ++nj) orow[nj * 16] = f2bf(acc[mi][nj][j]);
      } else {
        float* orow = (float*)OutV + row * N + bn0 + wc * 64 + (lane & 15);
#pragma unroll
        for (int nj = 0; nj < 4; ++nj) orow[nj * 16] = acc[mi][nj][j];
      }
    }
  }
}

// ---- weighted combine, IN-PLACE on T:
// h[m,r] = sum_n wf[m,n] * T[m, n*256+r];  T[m, n*256+r] <- wr[m,n] * h[m,r]
// one wave per row; lane covers r = lane*4 .. lane*4+3
__global__ void combine_kernel(u16* __restrict__ T, const float* __restrict__ Wf,
                               const float* __restrict__ Wr) {
  const int m = blockIdx.x * 4 + (threadIdx.x >> 6);
  const int lane = threadIdx.x & 63;
  u16* rowp = T + (size_t)m * 4096;
  float h0 = 0.f, h1 = 0.f, h2 = 0.f, h3 = 0.f;
#pragma unroll
  for (int n = 0; n < 16; ++n) {
    u16x4 v = *(const u16x4*)&rowp[n * 256 + lane * 4];
    const float wf = Wf[(size_t)m * 16 + n];
    h0 += wf * bf2f(v[0]); h1 += wf * bf2f(v[1]);
    h2 += wf * bf2f(v[2]); h3 += wf * bf2f(v[3]);
  }
#pragma unroll
  for (int n = 0; n < 16; ++n) {
    const float wr = Wr[(size_t)m * 16 + n];
    u16x4 o;
    o[0] = f2bf(wr * h0); o[1] = f2bf(wr * h1);
    o[2] = f2bf(wr * h2); o[3] = f2bf(wr * h3);
    *(u16x4*)&rowp[n * 256 + lane * 4] = o;
  }
}

extern "C" void kernel_launch(void* const* d_in, const int* in_sizes, int n_in,
                              void* d_out, int out_size, void* d_ws, size_t ws_size,
                              hipStream_t stream) {
  const float* x  = (const float*)d_in[0];   // [8192][1024]
  const float* F  = (const float*)d_in[1];   // [16][1024][256]
  const float* Rk = (const float*)d_in[2];   // [16][256][1024] == flat [4096][1024]
  const float* Wf = (const float*)d_in[3];   // [8192][16]
  const float* Wr = (const float*)d_in[4];   // [8192][16]
  float* out = (float*)d_out;                // [8192][1024]

  char* ws = (char*)d_ws;
  u16* X16 = (u16*)(ws);                 // 16 MB  x bf16 [8192][1024]
  u16* B1  = (u16*)(ws + (16u << 20));   //  8 MB  F^T per expert -> [(n,r)=4096][1024]
  u16* B2  = (u16*)(ws + (24u << 20));   //  8 MB  Rk flat transposed -> [1024][4096]
  u16* T   = (u16*)(ws + (32u << 20));   // 64 MB  T / H' bf16 [8192][4096] (in-place combine)
  // total 96 MB of d_ws

  // 1) casts / transposes
  cast_x_kernel<<<2048, 256, 0, stream>>>(x, X16, (M_TOK * 1024) / 4);
  tcast_kernel<<<dim3(8, 32, 16), 256, 0, stream>>>(F, B1, 1024, 256);    // [n][d][r]->[n][r][d]
  tcast_kernel<<<dim3(32, 128, 1), 256, 0, stream>>>(Rk, B2, 4096, 1024); // [4096][1024]->[1024][4096]

  // 2) T = X16 @ B1^T   (M=8192, N=4096, K=1024) -> bf16, grid 32x64 = 2048 blocks
  gemm_bt<16, true><<<dim3(32, 64), 256, 0, stream>>>(X16, B1, T, 4096, 1024);

  // 3) in-place: T <- wr ⊙ broadcast(h),  h = wf-weighted sum over column groups
  combine_kernel<<<2048, 256, 0, stream>>>(T, Wf, Wr);

  // 4) out = H' @ B2^T  (M=8192, N=1024, K=4096) -> f32, grid 8x64 = 512 blocks
  gemm_bt<64, false><<<dim3(8, 64), 256, 0, stream>>>(T, B2, out, 1024, 4096);
}

// Round 3
// 193.912 us; speedup vs baseline: 1.3781x; 1.2532x over previous
//
#include <hip/hip_runtime.h>

typedef unsigned short u16;
typedef unsigned int u32;
typedef __attribute__((ext_vector_type(4))) float f32x4;
typedef __attribute__((ext_vector_type(8))) short bf16x8;
typedef __attribute__((ext_vector_type(4))) unsigned short u16x4;

#define MFMA(a, b, c) __builtin_amdgcn_mfma_f32_16x16x32_bf16((a), (b), (c), 0, 0, 0)

static constexpr int M_TOK = 8192;  // B*S

__device__ __forceinline__ u16 f2bf(float f) {
  u32 u = __float_as_uint(f);
  return (u16)((u + 0x7FFFu + ((u >> 16) & 1u)) >> 16);  // RNE
}
__device__ __forceinline__ float bf2f(u16 b) {
  u32 u = ((u32)b) << 16;
  return __uint_as_float(u);
}
__device__ __forceinline__ void gload16(const u16* g, u16* l) {
  __builtin_amdgcn_global_load_lds(
      (const __attribute__((address_space(1))) u32*)(const void*)g,
      (__attribute__((address_space(3))) u32*)(void*)l, 16, 0, 0);
}

// ---- elementwise fp32 -> bf16 cast ----
__global__ void cast_x_kernel(const float* __restrict__ in, u16* __restrict__ out, int total4) {
  for (int i = blockIdx.x * blockDim.x + threadIdx.x; i < total4; i += gridDim.x * blockDim.x) {
    float4 v = ((const float4*)in)[i];
    u16x4 o;
    o[0] = f2bf(v.x); o[1] = f2bf(v.y); o[2] = f2bf(v.z); o[3] = f2bf(v.w);
    ((u16x4*)out)[i] = o;
  }
}

// ---- transpose + cast: in [z][P][Q] fp32 -> out [z][Q][P] bf16 ----
__global__ void tcast_kernel(const float* __restrict__ in, u16* __restrict__ out, int P, int Q) {
  __shared__ float tile[32][33];
  const int z = blockIdx.z;
  const int q0 = blockIdx.x * 32, p0 = blockIdx.y * 32;
  const float* src = in + (size_t)z * P * Q;
  u16* dst = out + (size_t)z * P * Q;
  const int tx = threadIdx.x & 31, ty = threadIdx.x >> 5;
#pragma unroll
  for (int k = 0; k < 4; ++k)
    tile[ty + k * 8][tx] = src[(size_t)(p0 + ty + k * 8) * Q + q0 + tx];
  __syncthreads();
#pragma unroll
  for (int k = 0; k < 4; ++k)
    dst[(size_t)(q0 + ty + k * 8) * P + p0 + tx] = f2bf(tile[tx][ty + k * 8]);
}

// ---- weighted combine, IN-PLACE on T ----
__global__ void combine_kernel(u16* __restrict__ T, const float* __restrict__ Wf,
                               const float* __restrict__ Wr) {
  const int m = blockIdx.x * 4 + (threadIdx.x >> 6);
  const int lane = threadIdx.x & 63;
  u16* rowp = T + (size_t)m * 4096;
  float h0 = 0.f, h1 = 0.f, h2 = 0.f, h3 = 0.f;
#pragma unroll
  for (int n = 0; n < 16; ++n) {
    u16x4 v = *(const u16x4*)&rowp[n * 256 + lane * 4];
    const float wf = Wf[(size_t)m * 16 + n];
    h0 += wf * bf2f(v[0]); h1 += wf * bf2f(v[1]);
    h2 += wf * bf2f(v[2]); h3 += wf * bf2f(v[3]);
  }
#pragma unroll
  for (int n = 0; n < 16; ++n) {
    const float wr = Wr[(size_t)m * 16 + n];
    u16x4 o;
    o[0] = f2bf(wr * h0); o[1] = f2bf(wr * h1);
    o[2] = f2bf(wr * h2); o[3] = f2bf(wr * h3);
    *(u16x4*)&rowp[n * 256 + lane * 4] = o;
  }
}

// ================= 256-row 8-phase GEMM (T2+T3+T4+T5) =================
// A: [M][K] bf16, Bm: [N][K] bf16 (k contiguous). Tile BM=256 x BN, BK=64.
// 8 waves (2M x 4N). LDS half-tiles 128x64 bf16 = 16KB, XOR-swizzled
// (byte ^= (row&7)<<4) via inverse-swizzled global source (linear gload_lds
// dest) + swizzled ds_read. 2-K-tile double buffer, counted vmcnt(4).
#define PH_BAR()                                     \
  do {                                               \
    __builtin_amdgcn_sched_barrier(0);               \
    __builtin_amdgcn_s_barrier();                    \
    asm volatile("s_waitcnt lgkmcnt(0)" ::: "memory"); \
    __builtin_amdgcn_sched_barrier(0);               \
  } while (0)
#define PH_END()                       \
  do {                                 \
    __builtin_amdgcn_sched_barrier(0); \
    __builtin_amdgcn_s_barrier();      \
  } while (0)

template <int BN, int NT, int OUTMODE>  // OUTMODE: 0 = bf16 store, 1 = f32 store
__global__ __launch_bounds__(512, 2) void gemm256(
    const u16* __restrict__ A, const u16* __restrict__ Bm, void* __restrict__ OutV,
    const int N, const int K) {
  constexpr int NJT = BN / 64;   // N-frags per wave (4 or 2)
  constexpr int NJQ = NJT / 2;   // frags per N-quadrant (2 or 1)
  constexpr int BH = BN / 128;   // B half-tiles (2 or 1)
  constexpr int NITER = NT / 2;
  static_assert(NITER >= 2, "");

  __shared__ u16 ldsA[2][2][8192];
  __shared__ u16 ldsB[2][BH][8192];

  const int tid = threadIdx.x;
  const int lane = tid & 63;
  const int wid = tid >> 6;
  const int wr = wid >> 2;  // 0..1 -> M half
  const int wc = wid & 3;   // 0..3 -> N quarter

  // XCD-aware bijective swizzle (nwg % 8 == 0 for all grids used)
  const int nwg = gridDim.x * gridDim.y;
  int wgid = blockIdx.y * gridDim.x + blockIdx.x;
  wgid = (wgid & 7) * (nwg >> 3) + (wgid >> 3);
  const int by = wgid / gridDim.x, bx = wgid - by * gridDim.x;
  const int m0 = by * 256, bn0 = bx * BN;

  const int arow = lane & 15;
  const int acol = (lane >> 4) * 16;       // byte col base within 128B row
  const int sw = (arow & 7) << 4;          // LDS XOR swizzle
  const int lo0 = arow * 128 + (acol ^ sw);        // ks=0 byte offset
  const int lo1 = arow * 128 + ((64 + acol) ^ sw); // ks=1 byte offset

  const u16* Abase = A + (size_t)m0 * K;
  const u16* Bbase = Bm + (size_t)bn0 * K;

  f32x4 acc[8][NJT];
#pragma unroll
  for (int i = 0; i < 8; ++i)
#pragma unroll
    for (int j = 0; j < NJT; ++j) acc[i][j] = (f32x4){0.f, 0.f, 0.f, 0.f};

  // stage one 128x64 half-tile (16KB): 2 x gload16 per thread, linear LDS
  // dest, inverse-swizzled global column.
  auto STAGE = [&](int b, int isB, int hf, int kt) {
    const u16* G = isB ? Bbase : Abase;
    u16* L = isB ? &ldsB[b][hf][0] : &ldsA[b][hf][0];
#pragma unroll
    for (int j = 0; j < 2; ++j) {
      const int q = j * 8192 + tid * 16;  // byte offset in half-tile
      const int grow = q >> 7;
      const int gcol = ((q & 127) ^ (((q >> 7) & 7) << 4)) >> 1;  // elems
      gload16(G + (size_t)(hf * 128 + grow) * K + kt * 64 + gcol,
              L + ((j * 8192 + wid * 1024) >> 1));
    }
  };

  auto LOAD_AV = [&](bf16x8 (&v)[4][2], int b, int mh) {
    const char* p = (const char*)&ldsA[b][wr][0] + mh * 8192;
#pragma unroll
    for (int mi = 0; mi < 4; ++mi) {
      v[mi][0] = *(const bf16x8*)(p + mi * 2048 + lo0);
      v[mi][1] = *(const bf16x8*)(p + mi * 2048 + lo1);
    }
  };
  auto LOAD_BV = [&](bf16x8 (&v)[NJQ][2], int b, int nq) {
#pragma unroll
    for (int nj = 0; nj < NJQ; ++nj) {
      const int rb = wc * (BN / 4) + (nq * NJQ + nj) * 16;  // tile row of B
      const char* p = (const char*)&ldsB[b][rb >> 7][0] + (rb & 127) * 128;
      v[nj][0] = *(const bf16x8*)(p + lo0);
      v[nj][1] = *(const bf16x8*)(p + lo1);
    }
  };

#define QUAD(AV, BV, MH, NQ)                                                   \
  do {                                                                         \
    _Pragma("unroll") for (int mi = 0; mi < 4; ++mi) {                         \
      _Pragma("unroll") for (int nj = 0; nj < NJQ; ++nj) {                     \
        acc[(MH)*4 + mi][(NQ)*NJQ + nj] =                                      \
            MFMA(AV[mi][0], BV[nj][0], acc[(MH)*4 + mi][(NQ)*NJQ + nj]);       \
        acc[(MH)*4 + mi][(NQ)*NJQ + nj] =                                      \
            MFMA(AV[mi][1], BV[nj][1], acc[(MH)*4 + mi][(NQ)*NJQ + nj]);       \
      }                                                                        \
    }                                                                          \
  } while (0)

  // ---- prologue: t0 fully + B0(t1), A0(t1); leaves 4 loads outstanding ----
  STAGE(0, 0, 0, 0);
  STAGE(0, 0, 1, 0);
  STAGE(0, 1, 0, 0);
  if constexpr (BH == 2) STAGE(0, 1, 1, 0);
  STAGE(1, 1, 0, 1);
  STAGE(1, 0, 0, 1);
  asm volatile("s_waitcnt vmcnt(4)" ::: "memory");
  __builtin_amdgcn_sched_barrier(0);
  __builtin_amdgcn_s_barrier();

  bf16x8 av[4][2], avh[4][2], bv0[NJQ][2], bv1[NJQ][2];

#pragma unroll 1
  for (int i = 0; i < NITER; ++i) {
    const int ta = 2 * i, tb = ta + 1;
    const bool st = (i + 1 < NITER);
    // ---- phase 1: reads av_lo(ta)+bv_N0(ta); stage A1(tb) ----
    LOAD_AV(av, 0, 0);
    LOAD_BV(bv0, 0, 0);
    STAGE(1, 0, 1, tb);
    PH_BAR();
    __builtin_amdgcn_s_setprio(1); QUAD(av, bv0, 0, 0); __builtin_amdgcn_s_setprio(0);
    PH_END();
    // ---- phase 2: reads bv_N1(ta); stage B1(tb) ----
    LOAD_BV(bv1, 0, 1);
    if constexpr (BH == 2) STAGE(1, 1, 1, tb);
    PH_BAR();
    __builtin_amdgcn_s_setprio(1); QUAD(av, bv1, 0, 1); __builtin_amdgcn_s_setprio(0);
    PH_END();
    // ---- phase 3: reads av_hi(ta); stage B0(ta+2) ----
    LOAD_AV(avh, 0, 1);
    if (st) STAGE(0, 1, 0, ta + 2);
    PH_BAR();
    __builtin_amdgcn_s_setprio(1); QUAD(avh, bv0, 1, 0); __builtin_amdgcn_s_setprio(0);
    PH_END();
    // ---- phase 4: stage A0(ta+2); counted vmcnt ----
    if (st) STAGE(0, 0, 0, ta + 2);
    PH_BAR();
    __builtin_amdgcn_s_setprio(1); QUAD(avh, bv1, 1, 1); __builtin_amdgcn_s_setprio(0);
    if (st) asm volatile("s_waitcnt vmcnt(4)" ::: "memory");
    else    asm volatile("s_waitcnt vmcnt(0)" ::: "memory");
    PH_END();
    // ---- phase 5: reads av_lo(tb)+bv_N0(tb); stage A1(ta+2) ----
    LOAD_AV(av, 1, 0);
    LOAD_BV(bv0, 1, 0);
    if (st) STAGE(0, 0, 1, ta + 2);
    PH_BAR();
    __builtin_amdgcn_s_setprio(1); QUAD(av, bv0, 0, 0); __builtin_amdgcn_s_setprio(0);
    PH_END();
    // ---- phase 6: reads bv_N1(tb); stage B1(ta+2) ----
    LOAD_BV(bv1, 1, 1);
    if constexpr (BH == 2) {
      if (st) STAGE(0, 1, 1, ta + 2);
    }
    PH_BAR();
    __builtin_amdgcn_s_setprio(1); QUAD(av, bv1, 0, 1); __builtin_amdgcn_s_setprio(0);
    PH_END();
    // ---- phase 7: reads av_hi(tb); stage B0(tb+2) ----
    LOAD_AV(avh, 1, 1);
    if (st) STAGE(1, 1, 0, tb + 2);
    PH_BAR();
    __builtin_amdgcn_s_setprio(1); QUAD(avh, bv0, 1, 0); __builtin_amdgcn_s_setprio(0);
    PH_END();
    // ---- phase 8: stage A0(tb+2); counted vmcnt ----
    if (st) STAGE(1, 0, 0, tb + 2);
    PH_BAR();
    __builtin_amdgcn_s_setprio(1); QUAD(avh, bv1, 1, 1); __builtin_amdgcn_s_setprio(0);
    if (st) asm volatile("s_waitcnt vmcnt(4)" ::: "memory");
    PH_END();
  }

  // ---- epilogue: C/D row = (lane>>4)*4 + j, col = lane&15 ----
#pragma unroll
  for (int MI = 0; MI < 8; ++MI) {
    const int row = m0 + wr * 128 + MI * 16 + (lane >> 4) * 4;
#pragma unroll
    for (int NJ = 0; NJ < NJT; ++NJ) {
      const int col = bn0 + wc * (BN / 4) + NJ * 16 + (lane & 15);
      if constexpr (OUTMODE == 0) {
        u16* p = (u16*)OutV + (size_t)row * N + col;
#pragma unroll
        for (int j = 0; j < 4; ++j) p[(size_t)j * N] = f2bf(acc[MI][NJ][j]);
      } else {
        float* p = (float*)OutV + (size_t)row * N + col;
#pragma unroll
        for (int j = 0; j < 4; ++j) p[(size_t)j * N] = acc[MI][NJ][j];
      }
    }
  }
}
#undef QUAD

extern "C" void kernel_launch(void* const* d_in, const int* in_sizes, int n_in,
                              void* d_out, int out_size, void* d_ws, size_t ws_size,
                              hipStream_t stream) {
  const float* x  = (const float*)d_in[0];   // [8192][1024]
  const float* F  = (const float*)d_in[1];   // [16][1024][256]
  const float* Rk = (const float*)d_in[2];   // [16][256][1024] == flat [4096][1024]
  const float* Wf = (const float*)d_in[3];   // [8192][16]
  const float* Wr = (const float*)d_in[4];   // [8192][16]
  float* out = (float*)d_out;                // [8192][1024]

  char* ws = (char*)d_ws;
  u16* X16 = (u16*)(ws);                 // 16 MB  x bf16 [8192][1024]
  u16* B1  = (u16*)(ws + (16u << 20));   //  8 MB  F^T  [(n,r)=4096][1024]
  u16* B2  = (u16*)(ws + (24u << 20));   //  8 MB  Rk^T [1024][4096]
  u16* T   = (u16*)(ws + (32u << 20));   // 64 MB  T / H' bf16 [8192][4096]

  // 1) casts / transposes
  cast_x_kernel<<<2048, 256, 0, stream>>>(x, X16, (M_TOK * 1024) / 4);
  tcast_kernel<<<dim3(8, 32, 16), 256, 0, stream>>>(F, B1, 1024, 256);
  tcast_kernel<<<dim3(32, 128, 1), 256, 0, stream>>>(Rk, B2, 4096, 1024);

  // 2) T = X16 @ B1^T  (M=8192, N=4096, K=1024), 256x256 tiles, 512 blocks
  gemm256<256, 16, 0><<<dim3(16, 32, 1), 512, 0, stream>>>(X16, B1, T, 4096, 1024);

  // 3) in-place: T <- wr ⊙ broadcast(h), h = wf-weighted column-group sum
  combine_kernel<<<2048, 256, 0, stream>>>(T, Wf, Wr);

  // 4) out = H' @ B2^T  (M=8192, N=1024, K=4096), 256x128 tiles, 256 blocks
  gemm256<128, 64, 1><<<dim3(8, 32, 1), 512, 0, stream>>>(T, B2, out, 1024, 4096);
}

// Round 4
// 187.238 us; speedup vs baseline: 1.4273x; 1.0356x over previous
//
#include <hip/hip_runtime.h>

typedef unsigned short u16;
typedef unsigned int u32;
typedef __attribute__((ext_vector_type(4))) float f32x4;
typedef __attribute__((ext_vector_type(8))) short bf16x8;
typedef __attribute__((ext_vector_type(4))) unsigned short u16x4;

#define MFMA(a, b, c) __builtin_amdgcn_mfma_f32_16x16x32_bf16((a), (b), (c), 0, 0, 0)

static constexpr int M_TOK = 8192;  // B*S

__device__ __forceinline__ u16 f2bf(float f) {
  u32 u = __float_as_uint(f);
  return (u16)((u + 0x7FFFu + ((u >> 16) & 1u)) >> 16);  // RNE
}
__device__ __forceinline__ float bf2f(u16 b) {
  u32 u = ((u32)b) << 16;
  return __uint_as_float(u);
}
__device__ __forceinline__ void gload16(const u16* g, u16* l) {
  __builtin_amdgcn_global_load_lds(
      (const __attribute__((address_space(1))) u32*)(const void*)g,
      (__attribute__((address_space(3))) u32*)(void*)l, 16, 0, 0);
}

// ---- elementwise fp32 -> bf16 cast ----
__global__ void cast_x_kernel(const float* __restrict__ in, u16* __restrict__ out, int total4) {
  for (int i = blockIdx.x * blockDim.x + threadIdx.x; i < total4; i += gridDim.x * blockDim.x) {
    float4 v = ((const float4*)in)[i];
    u16x4 o;
    o[0] = f2bf(v.x); o[1] = f2bf(v.y); o[2] = f2bf(v.z); o[3] = f2bf(v.w);
    ((u16x4*)out)[i] = o;
  }
}

// ---- transpose + cast: in [z][P][Q] fp32 -> out [z][Q][P] bf16 ----
__global__ void tcast_kernel(const float* __restrict__ in, u16* __restrict__ out, int P, int Q) {
  __shared__ float tile[32][33];
  const int z = blockIdx.z;
  const int q0 = blockIdx.x * 32, p0 = blockIdx.y * 32;
  const float* src = in + (size_t)z * P * Q;
  u16* dst = out + (size_t)z * P * Q;
  const int tx = threadIdx.x & 31, ty = threadIdx.x >> 5;
#pragma unroll
  for (int k = 0; k < 4; ++k)
    tile[ty + k * 8][tx] = src[(size_t)(p0 + ty + k * 8) * Q + q0 + tx];
  __syncthreads();
#pragma unroll
  for (int k = 0; k < 4; ++k)
    dst[(size_t)(q0 + ty + k * 8) * P + p0 + tx] = f2bf(tile[tx][ty + k * 8]);
}

// ---- weighted combine, IN-PLACE on T ----
__global__ void combine_kernel(u16* __restrict__ T, const float* __restrict__ Wf,
                               const float* __restrict__ Wr) {
  const int m = blockIdx.x * 4 + (threadIdx.x >> 6);
  const int lane = threadIdx.x & 63;
  u16* rowp = T + (size_t)m * 4096;
  float h0 = 0.f, h1 = 0.f, h2 = 0.f, h3 = 0.f;
#pragma unroll
  for (int n = 0; n < 16; ++n) {
    u16x4 v = *(const u16x4*)&rowp[n * 256 + lane * 4];
    const float wf = Wf[(size_t)m * 16 + n];
    h0 += wf * bf2f(v[0]); h1 += wf * bf2f(v[1]);
    h2 += wf * bf2f(v[2]); h3 += wf * bf2f(v[3]);
  }
#pragma unroll
  for (int n = 0; n < 16; ++n) {
    const float wr = Wr[(size_t)m * 16 + n];
    u16x4 o;
    o[0] = f2bf(wr * h0); o[1] = f2bf(wr * h1);
    o[2] = f2bf(wr * h2); o[3] = f2bf(wr * h3);
    *(u16x4*)&rowp[n * 256 + lane * 4] = o;
  }
}

// ================= 256-row 8-phase GEMM (T2+T3+T4+T5) =================
// A: [M][K] bf16, Bm: [N][K] bf16 (k contiguous). BM=256 x BN, BK=64.
// 8 waves. BH==2 (BN=256): 2Mx4N wave grid, 8 phases/iter (proven loop).
// BH==1 (BN=128): 4Mx2N wave grid (wave tile 64x64), 4 phases/iter with
// 16 MFMA/phase (same MFMA:barrier density as BH==2).
// LDS half-tiles 128x64 bf16 = 16KB, XOR-swizzled (byte ^= (row&7)<<4) via
// inverse-swizzled global source + swizzled ds_read. Counted vmcnt.
#define PH_BAR()                                     \
  do {                                               \
    __builtin_amdgcn_sched_barrier(0);               \
    __builtin_amdgcn_s_barrier();                    \
    asm volatile("s_waitcnt lgkmcnt(0)" ::: "memory"); \
    __builtin_amdgcn_sched_barrier(0);               \
  } while (0)
#define PH_END()                       \
  do {                                 \
    __builtin_amdgcn_sched_barrier(0); \
    __builtin_amdgcn_s_barrier();      \
  } while (0)

template <int BN, int NT, int OUTMODE>  // OUTMODE: 0 = bf16 store, 1 = f32 store
__global__ __launch_bounds__(512, 2) void gemm256(
    const u16* __restrict__ A, const u16* __restrict__ Bm, void* __restrict__ OutV,
    const int N, const int K) {
  constexpr int BH = BN / 128;   // B half-tiles (2 or 1)
  constexpr int AM = (BH == 2) ? 8 : 4;  // M-frags per wave
  constexpr int NITER = NT / 2;
  static_assert(NITER >= 2, "");

  __shared__ u16 ldsA[2][2][8192];
  __shared__ u16 ldsB[2][BH][8192];

  const int tid = threadIdx.x;
  const int lane = tid & 63;
  const int wid = tid >> 6;
  // wave grid: BH==2 -> 2Mx4N (wave 128x64); BH==1 -> 4Mx2N (wave 64x64)
  const int wrM = (BH == 2) ? (wid >> 2) : (wid >> 1);
  const int wcN = (BH == 2) ? (wid & 3) : (wid & 1);

  // XCD-aware bijective swizzle (nwg % 8 == 0 for all grids used)
  const int nwg = gridDim.x * gridDim.y;
  int wgid = blockIdx.y * gridDim.x + blockIdx.x;
  wgid = (wgid & 7) * (nwg >> 3) + (wgid >> 3);
  const int by = wgid / gridDim.x, bx = wgid - by * gridDim.x;
  const int m0 = by * 256, bn0 = bx * BN;

  const int arow = lane & 15;
  const int acol = (lane >> 4) * 16;       // byte col base within 128B row
  const int sw = (arow & 7) << 4;          // LDS XOR swizzle
  const int lo0 = arow * 128 + (acol ^ sw);        // ks=0 byte offset
  const int lo1 = arow * 128 + ((64 + acol) ^ sw); // ks=1 byte offset

  const u16* Abase = A + (size_t)m0 * K;
  const u16* Bbase = Bm + (size_t)bn0 * K;

  f32x4 acc[AM][4];
#pragma unroll
  for (int i = 0; i < AM; ++i)
#pragma unroll
    for (int j = 0; j < 4; ++j) acc[i][j] = (f32x4){0.f, 0.f, 0.f, 0.f};

  // stage one 128x64 half-tile (16KB): 2 x gload16 per thread, linear LDS
  // dest, inverse-swizzled global column.
  auto STAGE = [&](int b, int isB, int hf, int kt) {
    const u16* G = isB ? Bbase : Abase;
    u16* L = isB ? &ldsB[b][hf][0] : &ldsA[b][hf][0];
#pragma unroll
    for (int j = 0; j < 2; ++j) {
      const int q = j * 8192 + tid * 16;  // byte offset in half-tile
      const int grow = q >> 7;
      const int gcol = ((q & 127) ^ (((q >> 7) & 7) << 4)) >> 1;  // elems
      gload16(G + (size_t)(hf * 128 + grow) * K + kt * 64 + gcol,
              L + ((j * 8192 + wid * 1024) >> 1));
    }
  };

  auto LOAD_AV = [&](bf16x8 (&v)[4][2], int b, int mh) {
    const int arb = (BH == 2) ? (wrM * 128 + mh * 64) : (wrM * 64);
    const char* p = (const char*)&ldsA[b][0][0] + arb * 128;
#pragma unroll
    for (int mi = 0; mi < 4; ++mi) {
      v[mi][0] = *(const bf16x8*)(p + mi * 2048 + lo0);
      v[mi][1] = *(const bf16x8*)(p + mi * 2048 + lo1);
    }
  };
  auto LOAD_BV = [&](bf16x8 (&v)[2][2], int b, int nq) {
#pragma unroll
    for (int nj = 0; nj < 2; ++nj) {
      const int rb = wcN * 64 + (nq * 2 + nj) * 16;  // tile row of B
      const char* p = (const char*)&ldsB[b][0][0] + rb * 128;
      v[nj][0] = *(const bf16x8*)(p + lo0);
      v[nj][1] = *(const bf16x8*)(p + lo1);
    }
  };

#define QUAD(AV, BV, MH, NQ)                                                   \
  do {                                                                         \
    _Pragma("unroll") for (int mi = 0; mi < 4; ++mi) {                         \
      _Pragma("unroll") for (int nj = 0; nj < 2; ++nj) {                       \
        acc[(MH)*4 + mi][(NQ)*2 + nj] =                                        \
            MFMA(AV[mi][0], BV[nj][0], acc[(MH)*4 + mi][(NQ)*2 + nj]);         \
        acc[(MH)*4 + mi][(NQ)*2 + nj] =                                        \
            MFMA(AV[mi][1], BV[nj][1], acc[(MH)*4 + mi][(NQ)*2 + nj]);         \
      }                                                                        \
    }                                                                          \
  } while (0)

  bf16x8 av[4][2], avh[4][2], bv0[2][2], bv1[2][2];

  if constexpr (BH == 2) {
    // ---- prologue: t0 full + B0(t1), A0(t1); 4 loads outstanding ----
    STAGE(0, 0, 0, 0);
    STAGE(0, 0, 1, 0);
    STAGE(0, 1, 0, 0);
    STAGE(0, 1, 1, 0);
    STAGE(1, 1, 0, 1);
    STAGE(1, 0, 0, 1);
    asm volatile("s_waitcnt vmcnt(4)" ::: "memory");
    __builtin_amdgcn_sched_barrier(0);
    __builtin_amdgcn_s_barrier();

#pragma unroll 1
    for (int i = 0; i < NITER; ++i) {
      const int ta = 2 * i, tb = ta + 1;
      const bool st = (i + 1 < NITER);
      // phase 1
      LOAD_AV(av, 0, 0);
      LOAD_BV(bv0, 0, 0);
      STAGE(1, 0, 1, tb);
      PH_BAR();
      __builtin_amdgcn_s_setprio(1); QUAD(av, bv0, 0, 0); __builtin_amdgcn_s_setprio(0);
      PH_END();
      // phase 2
      LOAD_BV(bv1, 0, 1);
      STAGE(1, 1, 1, tb);
      PH_BAR();
      __builtin_amdgcn_s_setprio(1); QUAD(av, bv1, 0, 1); __builtin_amdgcn_s_setprio(0);
      PH_END();
      // phase 3
      LOAD_AV(avh, 0, 1);
      if (st) STAGE(0, 1, 0, ta + 2);
      PH_BAR();
      __builtin_amdgcn_s_setprio(1); QUAD(avh, bv0, 1, 0); __builtin_amdgcn_s_setprio(0);
      PH_END();
      // phase 4
      if (st) STAGE(0, 0, 0, ta + 2);
      PH_BAR();
      __builtin_amdgcn_s_setprio(1); QUAD(avh, bv1, 1, 1); __builtin_amdgcn_s_setprio(0);
      if (st) asm volatile("s_waitcnt vmcnt(4)" ::: "memory");
      else    asm volatile("s_waitcnt vmcnt(0)" ::: "memory");
      PH_END();
      // phase 5
      LOAD_AV(av, 1, 0);
      LOAD_BV(bv0, 1, 0);
      if (st) STAGE(0, 0, 1, ta + 2);
      PH_BAR();
      __builtin_amdgcn_s_setprio(1); QUAD(av, bv0, 0, 0); __builtin_amdgcn_s_setprio(0);
      PH_END();
      // phase 6
      LOAD_BV(bv1, 1, 1);
      if (st) STAGE(0, 1, 1, ta + 2);
      PH_BAR();
      __builtin_amdgcn_s_setprio(1); QUAD(av, bv1, 0, 1); __builtin_amdgcn_s_setprio(0);
      PH_END();
      // phase 7
      LOAD_AV(avh, 1, 1);
      if (st) STAGE(1, 1, 0, tb + 2);
      PH_BAR();
      __builtin_amdgcn_s_setprio(1); QUAD(avh, bv0, 1, 0); __builtin_amdgcn_s_setprio(0);
      PH_END();
      // phase 8
      if (st) STAGE(1, 0, 0, tb + 2);
      PH_BAR();
      __builtin_amdgcn_s_setprio(1); QUAD(avh, bv1, 1, 1); __builtin_amdgcn_s_setprio(0);
      if (st) asm volatile("s_waitcnt vmcnt(4)" ::: "memory");
      PH_END();
    }
  } else {
    // ===== BH==1: 4 phases/iter, wave tile 64x64, 16 MFMA/phase =====
    // prologue: t0 {A0,A1,B0} + A0(t1); vmcnt(2) -> t0 landed
    STAGE(0, 0, 0, 0);
    STAGE(0, 0, 1, 0);
    STAGE(0, 1, 0, 0);
    STAGE(1, 0, 0, 1);
    asm volatile("s_waitcnt vmcnt(2)" ::: "memory");
    __builtin_amdgcn_sched_barrier(0);
    __builtin_amdgcn_s_barrier();

#pragma unroll 1
    for (int i = 0; i < NITER; ++i) {
      const int ta = 2 * i, tb = ta + 1;
      const bool st = (i + 1 < NITER);
      // P1: reads buf0 {A, B q0}; stage A1(tb), B0(tb)
      LOAD_AV(av, 0, 0);
      LOAD_BV(bv0, 0, 0);
      STAGE(1, 0, 1, tb);
      STAGE(1, 1, 0, tb);
      PH_BAR();
      __builtin_amdgcn_s_setprio(1); QUAD(av, bv0, 0, 0); __builtin_amdgcn_s_setprio(0);
      PH_END();
      // P2: reads buf0 {B q1}; stage A0(ta+2); vmcnt -> tb landed
      LOAD_BV(bv1, 0, 1);
      if (st) STAGE(0, 0, 0, ta + 2);
      PH_BAR();
      __builtin_amdgcn_s_setprio(1); QUAD(av, bv1, 0, 1); __builtin_amdgcn_s_setprio(0);
      if (st) asm volatile("s_waitcnt vmcnt(2)" ::: "memory");
      else    asm volatile("s_waitcnt vmcnt(0)" ::: "memory");
      PH_END();
      // P3: reads buf1 {A, B q0}; stage A1(ta+2), B0(ta+2)
      LOAD_AV(av, 1, 0);
      LOAD_BV(bv0, 1, 0);
      if (st) { STAGE(0, 0, 1, ta + 2); STAGE(0, 1, 0, ta + 2); }
      PH_BAR();
      __builtin_amdgcn_s_setprio(1); QUAD(av, bv0, 0, 0); __builtin_amdgcn_s_setprio(0);
      PH_END();
      // P4: reads buf1 {B q1}; stage A0(tb+2); vmcnt -> ta+2 landed
      LOAD_BV(bv1, 1, 1);
      if (st) STAGE(1, 0, 0, tb + 2);
      PH_BAR();
      __builtin_amdgcn_s_setprio(1); QUAD(av, bv1, 0, 1); __builtin_amdgcn_s_setprio(0);
      if (st) asm volatile("s_waitcnt vmcnt(2)" ::: "memory");
      PH_END();
    }
  }

  // ---- epilogue: C/D row = (lane>>4)*4 + j, col = lane&15 ----
#pragma unroll
  for (int MI = 0; MI < AM; ++MI) {
    const int row = m0 + ((BH == 2) ? wrM * 128 : wrM * 64) + MI * 16 + (lane >> 4) * 4;
#pragma unroll
    for (int NJ = 0; NJ < 4; ++NJ) {
      const int col = bn0 + wcN * 64 + NJ * 16 + (lane & 15);
      if constexpr (OUTMODE == 0) {
        u16* p = (u16*)OutV + (size_t)row * N + col;
#pragma unroll
        for (int j = 0; j < 4; ++j) p[(size_t)j * N] = f2bf(acc[MI][NJ][j]);
      } else {
        float* p = (float*)OutV + (size_t)row * N + col;
#pragma unroll
        for (int j = 0; j < 4; ++j) p[(size_t)j * N] = acc[MI][NJ][j];
      }
    }
  }
}
#undef QUAD

extern "C" void kernel_launch(void* const* d_in, const int* in_sizes, int n_in,
                              void* d_out, int out_size, void* d_ws, size_t ws_size,
                              hipStream_t stream) {
  const float* x  = (const float*)d_in[0];   // [8192][1024]
  const float* F  = (const float*)d_in[1];   // [16][1024][256]
  const float* Rk = (const float*)d_in[2];   // [16][256][1024] == flat [4096][1024]
  const float* Wf = (const float*)d_in[3];   // [8192][16]
  const float* Wr = (const float*)d_in[4];   // [8192][16]
  float* out = (float*)d_out;                // [8192][1024]

  char* ws = (char*)d_ws;
  u16* X16 = (u16*)(ws);                 // 16 MB  x bf16 [8192][1024]
  u16* B1  = (u16*)(ws + (16u << 20));   //  8 MB  F^T  [(n,r)=4096][1024]
  u16* B2  = (u16*)(ws + (24u << 20));   //  8 MB  Rk^T [1024][4096]
  u16* T   = (u16*)(ws + (32u << 20));   // 64 MB  T / H' bf16 [8192][4096]

  // 1) casts / transposes
  cast_x_kernel<<<2048, 256, 0, stream>>>(x, X16, (M_TOK * 1024) / 4);
  tcast_kernel<<<dim3(8, 32, 16), 256, 0, stream>>>(F, B1, 1024, 256);
  tcast_kernel<<<dim3(32, 128, 1), 256, 0, stream>>>(Rk, B2, 4096, 1024);

  // 2) T = X16 @ B1^T  (M=8192, N=4096, K=1024), 256x256 tiles, 512 blocks
  gemm256<256, 16, 0><<<dim3(16, 32, 1), 512, 0, stream>>>(X16, B1, T, 4096, 1024);

  // 3) in-place: T <- wr ⊙ broadcast(h), h = wf-weighted column-group sum
  combine_kernel<<<2048, 256, 0, stream>>>(T, Wf, Wr);

  // 4) out = H' @ B2^T  (M=8192, N=1024, K=4096), 256x128 tiles, 256 blocks
  gemm256<128, 64, 1><<<dim3(8, 32, 1), 512, 0, stream>>>(T, B2, out, 1024, 4096);
}

// Round 5
// 180.904 us; speedup vs baseline: 1.4772x; 1.0350x over previous
//
#include <hip/hip_runtime.h>

typedef unsigned short u16;
typedef unsigned int u32;
typedef __attribute__((ext_vector_type(4))) float f32x4;
typedef __attribute__((ext_vector_type(8))) short bf16x8;
typedef __attribute__((ext_vector_type(4))) unsigned short u16x4;

#define MFMA(a, b, c) __builtin_amdgcn_mfma_f32_16x16x32_bf16((a), (b), (c), 0, 0, 0)

static constexpr int M_TOK = 8192;  // B*S

__device__ __forceinline__ u16 f2bf(float f) {
  u32 u = __float_as_uint(f);
  return (u16)((u + 0x7FFFu + ((u >> 16) & 1u)) >> 16);  // RNE
}
__device__ __forceinline__ float bf2f(u16 b) {
  u32 u = ((u32)b) << 16;
  return __uint_as_float(u);
}
__device__ __forceinline__ void gload16(const u16* g, u16* l) {
  __builtin_amdgcn_global_load_lds(
      (const __attribute__((address_space(1))) u32*)(const void*)g,
      (__attribute__((address_space(3))) u32*)(void*)l, 16, 0, 0);
}

#define PH_BAR()                                     \
  do {                                               \
    __builtin_amdgcn_sched_barrier(0);               \
    __builtin_amdgcn_s_barrier();                    \
    asm volatile("s_waitcnt lgkmcnt(0)" ::: "memory"); \
    __builtin_amdgcn_sched_barrier(0);               \
  } while (0)
#define PH_END()                       \
  do {                                 \
    __builtin_amdgcn_sched_barrier(0); \
    __builtin_amdgcn_s_barrier();      \
  } while (0)

// ---- elementwise fp32 -> bf16 cast ----
__global__ void cast_x_kernel(const float* __restrict__ in, u16* __restrict__ out, int total4) {
  for (int i = blockIdx.x * blockDim.x + threadIdx.x; i < total4; i += gridDim.x * blockDim.x) {
    float4 v = ((const float4*)in)[i];
    u16x4 o;
    o[0] = f2bf(v.x); o[1] = f2bf(v.y); o[2] = f2bf(v.z); o[3] = f2bf(v.w);
    ((u16x4*)out)[i] = o;
  }
}

// ---- transpose + cast: in [z][P][Q] fp32 -> out [z][Q][P] bf16 ----
__global__ void tcast_kernel(const float* __restrict__ in, u16* __restrict__ out, int P, int Q) {
  __shared__ float tile[32][33];
  const int z = blockIdx.z;
  const int q0 = blockIdx.x * 32, p0 = blockIdx.y * 32;
  const float* src = in + (size_t)z * P * Q;
  u16* dst = out + (size_t)z * P * Q;
  const int tx = threadIdx.x & 31, ty = threadIdx.x >> 5;
#pragma unroll
  for (int k = 0; k < 4; ++k)
    tile[ty + k * 8][tx] = src[(size_t)(p0 + ty + k * 8) * Q + q0 + tx];
  __syncthreads();
#pragma unroll
  for (int k = 0; k < 4; ++k)
    dst[(size_t)(q0 + ty + k * 8) * P + p0 + tx] = f2bf(tile[tx][ty + k * 8]);
}

// ---- h[m,r] = sum_n wf[m,n] * T[m, n*256+r] -> bf16 ----
__global__ void combine_h(const u16* __restrict__ T, const float* __restrict__ Wf,
                          u16* __restrict__ h) {
  const int m = blockIdx.x * 4 + (threadIdx.x >> 6);
  const int lane = threadIdx.x & 63;
  const u16* rowp = T + (size_t)m * 4096;
  float h0 = 0.f, h1 = 0.f, h2 = 0.f, h3 = 0.f;
#pragma unroll
  for (int n = 0; n < 16; ++n) {
    u16x4 v = *(const u16x4*)&rowp[n * 256 + lane * 4];
    const float wf = Wf[(size_t)m * 16 + n];
    h0 += wf * bf2f(v[0]); h1 += wf * bf2f(v[1]);
    h2 += wf * bf2f(v[2]); h3 += wf * bf2f(v[3]);
  }
  u16x4 o;
  o[0] = f2bf(h0); o[1] = f2bf(h1); o[2] = f2bf(h2); o[3] = f2bf(h3);
  *(u16x4*)&h[(size_t)m * 256 + lane * 4] = o;
}

// ================= GEMM1: 256x256 8-phase (T2+T3+T4+T5), proven =================
template <int NT>
__global__ __launch_bounds__(512, 2) void gemm256(
    const u16* __restrict__ A, const u16* __restrict__ Bm, void* __restrict__ OutV,
    const int N, const int K) {
  constexpr int NITER = NT / 2;
  __shared__ u16 ldsA[2][2][8192];
  __shared__ u16 ldsB[2][2][8192];

  const int tid = threadIdx.x;
  const int lane = tid & 63;
  const int wid = tid >> 6;
  const int wr = wid >> 2, wc = wid & 3;

  const int nwg = gridDim.x * gridDim.y;
  int wgid = blockIdx.y * gridDim.x + blockIdx.x;
  wgid = (wgid & 7) * (nwg >> 3) + (wgid >> 3);
  const int by = wgid / gridDim.x, bx = wgid - by * gridDim.x;
  const int m0 = by * 256, bn0 = bx * 256;

  const int arow = lane & 15;
  const int acol = (lane >> 4) * 16;
  const int sw = (arow & 7) << 4;
  const int lo0 = arow * 128 + (acol ^ sw);
  const int lo1 = arow * 128 + ((64 + acol) ^ sw);

  const u16* Abase = A + (size_t)m0 * K;
  const u16* Bbase = Bm + (size_t)bn0 * K;

  f32x4 acc[8][4];
#pragma unroll
  for (int i = 0; i < 8; ++i)
#pragma unroll
    for (int j = 0; j < 4; ++j) acc[i][j] = (f32x4){0.f, 0.f, 0.f, 0.f};

  auto STAGE = [&](int b, int isB, int hf, int kt) {
    const u16* G = isB ? Bbase : Abase;
    u16* L = isB ? &ldsB[b][hf][0] : &ldsA[b][hf][0];
#pragma unroll
    for (int j = 0; j < 2; ++j) {
      const int q = j * 8192 + tid * 16;
      const int grow = q >> 7;
      const int gcol = ((q & 127) ^ (((q >> 7) & 7) << 4)) >> 1;
      gload16(G + (size_t)(hf * 128 + grow) * K + kt * 64 + gcol,
              L + ((j * 8192 + wid * 1024) >> 1));
    }
  };
  auto LOAD_AV = [&](bf16x8 (&v)[4][2], int b, int mh) {
    const char* p = (const char*)&ldsA[b][0][0] + (wr * 128 + mh * 64) * 128;
#pragma unroll
    for (int mi = 0; mi < 4; ++mi) {
      v[mi][0] = *(const bf16x8*)(p + mi * 2048 + lo0);
      v[mi][1] = *(const bf16x8*)(p + mi * 2048 + lo1);
    }
  };
  auto LOAD_BV = [&](bf16x8 (&v)[2][2], int b, int nq) {
#pragma unroll
    for (int nj = 0; nj < 2; ++nj) {
      const int rb = wc * 64 + (nq * 2 + nj) * 16;
      const char* p = (const char*)&ldsB[b][0][0] + rb * 128;
      v[nj][0] = *(const bf16x8*)(p + lo0);
      v[nj][1] = *(const bf16x8*)(p + lo1);
    }
  };

#define QUAD(AV, BV, MH, NQ)                                                   \
  do {                                                                         \
    _Pragma("unroll") for (int mi = 0; mi < 4; ++mi) {                         \
      _Pragma("unroll") for (int nj = 0; nj < 2; ++nj) {                       \
        acc[(MH)*4 + mi][(NQ)*2 + nj] =                                        \
            MFMA(AV[mi][0], BV[nj][0], acc[(MH)*4 + mi][(NQ)*2 + nj]);         \
        acc[(MH)*4 + mi][(NQ)*2 + nj] =                                        \
            MFMA(AV[mi][1], BV[nj][1], acc[(MH)*4 + mi][(NQ)*2 + nj]);         \
      }                                                                        \
    }                                                                          \
  } while (0)

  bf16x8 av[4][2], avh[4][2], bv0[2][2], bv1[2][2];

  STAGE(0, 0, 0, 0); STAGE(0, 0, 1, 0); STAGE(0, 1, 0, 0); STAGE(0, 1, 1, 0);
  STAGE(1, 1, 0, 1); STAGE(1, 0, 0, 1);
  asm volatile("s_waitcnt vmcnt(4)" ::: "memory");
  __builtin_amdgcn_sched_barrier(0);
  __builtin_amdgcn_s_barrier();

#pragma unroll 1
  for (int i = 0; i < NITER; ++i) {
    const int ta = 2 * i, tb = ta + 1;
    const bool st = (i + 1 < NITER);
    LOAD_AV(av, 0, 0); LOAD_BV(bv0, 0, 0); STAGE(1, 0, 1, tb);
    PH_BAR();
    __builtin_amdgcn_s_setprio(1); QUAD(av, bv0, 0, 0); __builtin_amdgcn_s_setprio(0);
    PH_END();
    LOAD_BV(bv1, 0, 1); STAGE(1, 1, 1, tb);
    PH_BAR();
    __builtin_amdgcn_s_setprio(1); QUAD(av, bv1, 0, 1); __builtin_amdgcn_s_setprio(0);
    PH_END();
    LOAD_AV(avh, 0, 1); if (st) STAGE(0, 1, 0, ta + 2);
    PH_BAR();
    __builtin_amdgcn_s_setprio(1); QUAD(avh, bv0, 1, 0); __builtin_amdgcn_s_setprio(0);
    PH_END();
    if (st) STAGE(0, 0, 0, ta + 2);
    PH_BAR();
    __builtin_amdgcn_s_setprio(1); QUAD(avh, bv1, 1, 1); __builtin_amdgcn_s_setprio(0);
    if (st) asm volatile("s_waitcnt vmcnt(4)" ::: "memory");
    else    asm volatile("s_waitcnt vmcnt(0)" ::: "memory");
    PH_END();
    LOAD_AV(av, 1, 0); LOAD_BV(bv0, 1, 0); if (st) STAGE(0, 0, 1, ta + 2);
    PH_BAR();
    __builtin_amdgcn_s_setprio(1); QUAD(av, bv0, 0, 0); __builtin_amdgcn_s_setprio(0);
    PH_END();
    LOAD_BV(bv1, 1, 1); if (st) STAGE(0, 1, 1, ta + 2);
    PH_BAR();
    __builtin_amdgcn_s_setprio(1); QUAD(av, bv1, 0, 1); __builtin_amdgcn_s_setprio(0);
    PH_END();
    LOAD_AV(avh, 1, 1); if (st) STAGE(1, 1, 0, tb + 2);
    PH_BAR();
    __builtin_amdgcn_s_setprio(1); QUAD(avh, bv0, 1, 0); __builtin_amdgcn_s_setprio(0);
    PH_END();
    if (st) STAGE(1, 0, 0, tb + 2);
    PH_BAR();
    __builtin_amdgcn_s_setprio(1); QUAD(avh, bv1, 1, 1); __builtin_amdgcn_s_setprio(0);
    if (st) asm volatile("s_waitcnt vmcnt(4)" ::: "memory");
    PH_END();
  }

#pragma unroll
  for (int MI = 0; MI < 8; ++MI) {
    const int row = m0 + wr * 128 + MI * 16 + (lane >> 4) * 4;
#pragma unroll
    for (int NJ = 0; NJ < 4; ++NJ) {
      const int col = bn0 + wc * 64 + NJ * 16 + (lane & 15);
      u16* p = (u16*)OutV + (size_t)row * N + col;
#pragma unroll
      for (int j = 0; j < 4; ++j) p[(size_t)j * N] = f2bf(acc[MI][NJ][j]);
    }
  }
}
#undef QUAD

// ============ GEMM2: weight-folded, A(h)-resident-in-registers ============
// out[m,d] = sum_n wr[m,n] * (h[m,:] @ Rt[n][d,:])
// BM=128, BN=128, 8 waves = 2(kh) x 2(M) x 2(N); wave tile 64x64, each wave
// owns half of K(=256 per n). A held in 64 VGPR; B pipelined via 4 pair-bufs,
// counted vmcnt(8); per-n fold acc_t += wr * acc_g; kh-reduce in epilogue.
__global__ __launch_bounds__(512, 2) void gemm_fold(
    const u16* __restrict__ A,    // h  [8192][256] bf16
    const u16* __restrict__ Bn,   // Rt [16][1024][256] bf16
    const float* __restrict__ W,  // Wr [8192][16] f32
    float* __restrict__ Out) {    // [8192][1024] f32
  __shared__ u16 ldsB[8][8192];   // 128 KB: 4 pair-buffers of 2 half-tiles
  __shared__ u16 Wlds[16][264];   // bf16 weights, [n][row]

  const int tid = threadIdx.x;
  const int lane = tid & 63;
  const int wid = tid >> 6;
  const int kh = wid >> 2;         // k-half
  const int wrM = (wid >> 1) & 1;  // M half (64 rows)
  const int wcN = wid & 1;         // N half (64 cols)

  const int nwg = gridDim.x * gridDim.y;  // 512
  int wgid = blockIdx.y * gridDim.x + blockIdx.x;
  wgid = (wgid & 7) * (nwg >> 3) + (wgid >> 3);
  const int by = wgid / gridDim.x, bx = wgid - by * gridDim.x;
  const int m0 = by * 128, d0 = bx * 128;

  const int arow = lane & 15;
  const int acol = (lane >> 4) * 16;
  const int sw = (arow & 7) << 4;
  const int lo0 = arow * 128 + (acol ^ sw);
  const int lo1 = arow * 128 + ((64 + acol) ^ sw);

  // weights -> LDS (bf16, transposed)
  for (int i = tid; i < 128 * 16; i += 512) {
    const int row = i >> 4, n = i & 15;
    Wlds[n][row] = f2bf(W[(size_t)(m0 + row) * 16 + n]);
  }

  // ---- A prologue: stage h-tile 128x256 as 4 half-tiles, read to regs ----
  auto ASTAGE = [&](int kt) {
    const u16* G = A + (size_t)m0 * 256;
    u16* L = &ldsB[kt][0];
#pragma unroll
    for (int j = 0; j < 2; ++j) {
      const int q = j * 8192 + tid * 16;
      const int grow = q >> 7;
      const int gcol = ((q & 127) ^ (((q >> 7) & 7) << 4)) >> 1;
      gload16(G + (size_t)grow * 256 + kt * 64 + gcol, L + ((j * 8192 + wid * 1024) >> 1));
    }
  };
  ASTAGE(0); ASTAGE(1); ASTAGE(2); ASTAGE(3);
  __syncthreads();
  bf16x8 avk[4][4];  // [kc][mi], kc = wave's 4 k-chunks of 32 within its half
#pragma unroll
  for (int c2 = 0; c2 < 2; ++c2) {
#pragma unroll
    for (int mi = 0; mi < 4; ++mi) {
      const char* p = (const char*)&ldsB[kh * 2 + c2][0] + (wrM * 64 + mi * 16) * 128;
      avk[c2 * 2 + 0][mi] = *(const bf16x8*)(p + lo0);
      avk[c2 * 2 + 1][mi] = *(const bf16x8*)(p + lo1);
    }
  }
  __syncthreads();

  // ---- B pipeline ----
  auto BSTAGE = [&](int ss) {  // stage pair-buffer for superstep ss (4 gloads/thr)
    const int n = ss >> 1, h = ss & 1, p = ss & 3;
    const u16* G = Bn + ((size_t)n * 1024 + d0) * 256;
#pragma unroll
    for (int t = 0; t < 2; ++t) {
      u16* L = &ldsB[2 * p + t][0];
      const int kt = h + 2 * t;
#pragma unroll
      for (int j = 0; j < 2; ++j) {
        const int q = j * 8192 + tid * 16;
        const int grow = q >> 7;
        const int gcol = ((q & 127) ^ (((q >> 7) & 7) << 4)) >> 1;
        gload16(G + (size_t)grow * 256 + kt * 64 + gcol, L + ((j * 8192 + wid * 1024) >> 1));
      }
    }
  };

  f32x4 acc_t[4][4], acc_g[4][4];
#pragma unroll
  for (int mi = 0; mi < 4; ++mi)
#pragma unroll
    for (int nj = 0; nj < 4; ++nj) {
      acc_t[mi][nj] = (f32x4){0.f, 0.f, 0.f, 0.f};
      acc_g[mi][nj] = (f32x4){0.f, 0.f, 0.f, 0.f};
    }
  bf16x8 bv[4][2];

  BSTAGE(0); BSTAGE(1); BSTAGE(2);
  asm volatile("s_waitcnt vmcnt(8)" ::: "memory");
  __builtin_amdgcn_sched_barrier(0);
  __builtin_amdgcn_s_barrier();

  // h passed as compile-time literal to keep avk indexing static (rule 20)
  auto SSTEP = [&](int ss, int h, bool do_stage, int vmsel) {
    const int p = ss & 3;
    const char* pB = (const char*)&ldsB[2 * p + kh][0];
#pragma unroll
    for (int nj = 0; nj < 4; ++nj) {
      const char* q = pB + (wcN * 64 + nj * 16) * 128;
      bv[nj][0] = *(const bf16x8*)(q + lo0);
      bv[nj][1] = *(const bf16x8*)(q + lo1);
    }
    if (do_stage) BSTAGE(ss + 3);
    PH_BAR();
    __builtin_amdgcn_s_setprio(1);
#pragma unroll
    for (int mi = 0; mi < 4; ++mi)
#pragma unroll
      for (int nj = 0; nj < 4; ++nj) {
        acc_g[mi][nj] = MFMA(avk[2 * h + 0][mi], bv[nj][0], acc_g[mi][nj]);
        acc_g[mi][nj] = MFMA(avk[2 * h + 1][mi], bv[nj][1], acc_g[mi][nj]);
      }
    __builtin_amdgcn_s_setprio(0);
    if (vmsel == 8)      asm volatile("s_waitcnt vmcnt(8)" ::: "memory");
    else if (vmsel == 4) asm volatile("s_waitcnt vmcnt(4)" ::: "memory");
    else if (vmsel == 0) asm volatile("s_waitcnt vmcnt(0)" ::: "memory");
    PH_END();
  };
  auto FOLD = [&](int n) {
#pragma unroll
    for (int mi = 0; mi < 4; ++mi) {
      const int rbase = wrM * 64 + mi * 16 + (lane >> 4) * 4;
      u16x4 wq = *(const u16x4*)&Wlds[n][rbase];
      const float w0 = bf2f(wq[0]), w1 = bf2f(wq[1]), w2 = bf2f(wq[2]), w3 = bf2f(wq[3]);
#pragma unroll
      for (int nj = 0; nj < 4; ++nj) {
        acc_t[mi][nj][0] += w0 * acc_g[mi][nj][0];
        acc_t[mi][nj][1] += w1 * acc_g[mi][nj][1];
        acc_t[mi][nj][2] += w2 * acc_g[mi][nj][2];
        acc_t[mi][nj][3] += w3 * acc_g[mi][nj][3];
        acc_g[mi][nj] = (f32x4){0.f, 0.f, 0.f, 0.f};
      }
    }
  };

#pragma unroll 1
  for (int nn = 0; nn < 14; ++nn) {
    SSTEP(nn * 2 + 0, 0, true, 8);
    SSTEP(nn * 2 + 1, 1, true, 8);
    FOLD(nn);
  }
  SSTEP(28, 0, true, 8);
  SSTEP(29, 1, false, 4);
  FOLD(14);
  SSTEP(30, 0, false, 0);
  SSTEP(31, 1, false, -1);
  FOLD(15);

  // ---- epilogue: kh-reduce via LDS, then store f32 ----
  __syncthreads();
  float* red = (float*)&ldsB[0][0];
  const int reg = (wrM * 2 + wcN) * 4096;  // 64x64 f32 region per (wrM,wcN)
  if (kh == 1) {
#pragma unroll
    for (int mi = 0; mi < 4; ++mi)
#pragma unroll
      for (int j = 0; j < 4; ++j) {
        const int r = mi * 16 + (lane >> 4) * 4 + j;
#pragma unroll
        for (int nj = 0; nj < 4; ++nj)
          red[reg + r * 64 + nj * 16 + (lane & 15)] = acc_t[mi][nj][j];
      }
  }
  __syncthreads();
  if (kh == 0) {
#pragma unroll
    for (int mi = 0; mi < 4; ++mi) {
      const int rr = mi * 16 + (lane >> 4) * 4;
#pragma unroll
      for (int j = 0; j < 4; ++j) {
        float* orow = Out + (size_t)(m0 + wrM * 64 + rr + j) * 1024 + d0 + wcN * 64 + (lane & 15);
#pragma unroll
        for (int nj = 0; nj < 4; ++nj)
          orow[nj * 16] = acc_t[mi][nj][j] + red[reg + (rr + j) * 64 + nj * 16 + (lane & 15)];
      }
    }
  }
}

extern "C" void kernel_launch(void* const* d_in, const int* in_sizes, int n_in,
                              void* d_out, int out_size, void* d_ws, size_t ws_size,
                              hipStream_t stream) {
  const float* x  = (const float*)d_in[0];   // [8192][1024]
  const float* F  = (const float*)d_in[1];   // [16][1024][256]
  const float* Rk = (const float*)d_in[2];   // [16][256][1024]
  const float* Wf = (const float*)d_in[3];   // [8192][16]
  const float* Wr = (const float*)d_in[4];   // [8192][16]
  float* out = (float*)d_out;                // [8192][1024]

  char* ws = (char*)d_ws;
  u16* X16 = (u16*)(ws);                 // 16 MB  x bf16 [8192][1024]
  u16* B1  = (u16*)(ws + (16u << 20));   //  8 MB  F^T  [(n,r)=4096][1024]
  u16* Rt  = (u16*)(ws + (24u << 20));   //  8 MB  Rk^T [16][1024][256]
  u16* T   = (u16*)(ws + (32u << 20));   // 64 MB  T bf16 [8192][4096]
  u16* h16 = (u16*)(ws);                 //  4 MB  h bf16 [8192][256] (reuses X16; X16 dead after GEMM1)

  // 1) casts / transposes
  cast_x_kernel<<<2048, 256, 0, stream>>>(x, X16, (M_TOK * 1024) / 4);
  tcast_kernel<<<dim3(8, 32, 16), 256, 0, stream>>>(F, B1, 1024, 256);    // [n][d][r]->[n][r][d]
  tcast_kernel<<<dim3(32, 8, 16), 256, 0, stream>>>(Rk, Rt, 256, 1024);   // [n][r][d]->[n][d][r]

  // 2) T = X16 @ B1^T  (M=8192, N=4096, K=1024), 512 blocks
  gemm256<16><<<dim3(16, 32, 1), 512, 0, stream>>>(X16, B1, T, 4096, 1024);

  // 3) h = wf-weighted column-group sum of T (bf16, 4 MB)
  combine_h<<<2048, 256, 0, stream>>>(T, Wf, h16);

  // 4) out = sum_n wr_n * (h @ Rt[n]), A-resident weight-folded GEMM, 512 blocks
  gemm_fold<<<dim3(8, 64, 1), 512, 0, stream>>>(h16, Rt, Wr, out);
}

// Round 6
// 171.000 us; speedup vs baseline: 1.5628x; 1.0579x over previous
//
#include <hip/hip_runtime.h>

typedef unsigned short u16;
typedef unsigned int u32;
typedef __attribute__((ext_vector_type(4))) float f32x4;
typedef __attribute__((ext_vector_type(8))) short bf16x8;
typedef __attribute__((ext_vector_type(4))) unsigned short u16x4;

#define MFMA(a, b, c) __builtin_amdgcn_mfma_f32_16x16x32_bf16((a), (b), (c), 0, 0, 0)

static constexpr int M_TOK = 8192;  // B*S

__device__ __forceinline__ u16 f2bf(float f) {
  u32 u = __float_as_uint(f);
  return (u16)((u + 0x7FFFu + ((u >> 16) & 1u)) >> 16);  // RNE
}
__device__ __forceinline__ float bf2f(u16 b) {
  u32 u = ((u32)b) << 16;
  return __uint_as_float(u);
}
__device__ __forceinline__ void gload16(const u16* g, u16* l) {
  __builtin_amdgcn_global_load_lds(
      (const __attribute__((address_space(1))) u32*)(const void*)g,
      (__attribute__((address_space(3))) u32*)(void*)l, 16, 0, 0);
}

#define PH_BAR()                                     \
  do {                                               \
    __builtin_amdgcn_sched_barrier(0);               \
    __builtin_amdgcn_s_barrier();                    \
    asm volatile("s_waitcnt lgkmcnt(0)" ::: "memory"); \
    __builtin_amdgcn_sched_barrier(0);               \
  } while (0)
#define PH_END()                       \
  do {                                 \
    __builtin_amdgcn_sched_barrier(0); \
    __builtin_amdgcn_s_barrier();      \
  } while (0)

// ---- elementwise fp32 -> bf16 cast ----
__global__ void cast_x_kernel(const float* __restrict__ in, u16* __restrict__ out, int total4) {
  for (int i = blockIdx.x * blockDim.x + threadIdx.x; i < total4; i += gridDim.x * blockDim.x) {
    float4 v = ((const float4*)in)[i];
    u16x4 o;
    o[0] = f2bf(v.x); o[1] = f2bf(v.y); o[2] = f2bf(v.z); o[3] = f2bf(v.w);
    ((u16x4*)out)[i] = o;
  }
}

// ---- transpose + cast: in [z][P][Q] fp32 -> out [z][Q][P] bf16 ----
__global__ void tcast_kernel(const float* __restrict__ in, u16* __restrict__ out, int P, int Q) {
  __shared__ float tile[32][33];
  const int z = blockIdx.z;
  const int q0 = blockIdx.x * 32, p0 = blockIdx.y * 32;
  const float* src = in + (size_t)z * P * Q;
  u16* dst = out + (size_t)z * P * Q;
  const int tx = threadIdx.x & 31, ty = threadIdx.x >> 5;
#pragma unroll
  for (int k = 0; k < 4; ++k)
    tile[ty + k * 8][tx] = src[(size_t)(p0 + ty + k * 8) * Q + q0 + tx];
  __syncthreads();
#pragma unroll
  for (int k = 0; k < 4; ++k)
    dst[(size_t)(q0 + ty + k * 8) * P + p0 + tx] = f2bf(tile[tx][ty + k * 8]);
}

// ---- h[m,r] = sum_n wf[m,n] * T[m, n*256+r] -> bf16 ----
__global__ void combine_h(const u16* __restrict__ T, const float* __restrict__ Wf,
                          u16* __restrict__ h) {
  const int m = blockIdx.x * 4 + (threadIdx.x >> 6);
  const int lane = threadIdx.x & 63;
  const u16* rowp = T + (size_t)m * 4096;
  float h0 = 0.f, h1 = 0.f, h2 = 0.f, h3 = 0.f;
#pragma unroll
  for (int n = 0; n < 16; ++n) {
    u16x4 v = *(const u16x4*)&rowp[n * 256 + lane * 4];
    const float wf = Wf[(size_t)m * 16 + n];
    h0 += wf * bf2f(v[0]); h1 += wf * bf2f(v[1]);
    h2 += wf * bf2f(v[2]); h3 += wf * bf2f(v[3]);
  }
  u16x4 o;
  o[0] = f2bf(h0); o[1] = f2bf(h1); o[2] = f2bf(h2); o[3] = f2bf(h3);
  *(u16x4*)&h[(size_t)m * 256 + lane * 4] = o;
}

// ================= GEMM1: 256x256, merged 4-phase (32 MFMA/phase) =================
template <int NT>
__global__ __launch_bounds__(512, 2) void gemm256(
    const u16* __restrict__ A, const u16* __restrict__ Bm, void* __restrict__ OutV,
    const int N, const int K) {
  constexpr int NITER = NT / 2;
  __shared__ u16 ldsA[2][2][8192];
  __shared__ u16 ldsB[2][2][8192];

  const int tid = threadIdx.x;
  const int lane = tid & 63;
  const int wid = tid >> 6;
  const int wr = wid >> 2, wc = wid & 3;

  // L2-aware chunked XCD swizzle: each XCD chunk = 4 bx x 8 by (B slice 2MB <= L2)
  // grid is 16 x 32 = 512 blocks
  {
  }
  const int L = blockIdx.y * gridDim.x + blockIdx.x;
  const int ordered = (L & 7) * 64 + (L >> 3);
  const int cid = ordered >> 5, win = ordered & 31;
  const int bx = (cid & 3) * 4 + (win & 3);
  const int by = (cid >> 2) * 8 + (win >> 2);
  const int m0 = by * 256, bn0 = bx * 256;

  const int arow = lane & 15;
  const int acol = (lane >> 4) * 16;
  const int sw = (arow & 7) << 4;
  const int lo0 = arow * 128 + (acol ^ sw);
  const int lo1 = arow * 128 + ((64 + acol) ^ sw);

  const u16* Abase = A + (size_t)m0 * K;
  const u16* Bbase = Bm + (size_t)bn0 * K;

  f32x4 acc[8][4];
#pragma unroll
  for (int i = 0; i < 8; ++i)
#pragma unroll
    for (int j = 0; j < 4; ++j) acc[i][j] = (f32x4){0.f, 0.f, 0.f, 0.f};

  auto STAGE = [&](int b, int isB, int hf, int kt) {
    const u16* G = isB ? Bbase : Abase;
    u16* L2p = isB ? &ldsB[b][hf][0] : &ldsA[b][hf][0];
#pragma unroll
    for (int j = 0; j < 2; ++j) {
      const int q = j * 8192 + tid * 16;
      const int grow = q >> 7;
      const int gcol = ((q & 127) ^ (((q >> 7) & 7) << 4)) >> 1;
      gload16(G + (size_t)(hf * 128 + grow) * K + kt * 64 + gcol,
              L2p + ((j * 8192 + wid * 1024) >> 1));
    }
  };
  auto LOAD_AV = [&](bf16x8 (&v)[4][2], int b, int mh) {
    const char* p = (const char*)&ldsA[b][0][0] + (wr * 128 + mh * 64) * 128;
#pragma unroll
    for (int mi = 0; mi < 4; ++mi) {
      v[mi][0] = *(const bf16x8*)(p + mi * 2048 + lo0);
      v[mi][1] = *(const bf16x8*)(p + mi * 2048 + lo1);
    }
  };
  auto LOAD_BV = [&](bf16x8 (&v)[2][2], int b, int nq) {
#pragma unroll
    for (int nj = 0; nj < 2; ++nj) {
      const int rb = wc * 64 + (nq * 2 + nj) * 16;
      const char* p = (const char*)&ldsB[b][0][0] + rb * 128;
      v[nj][0] = *(const bf16x8*)(p + lo0);
      v[nj][1] = *(const bf16x8*)(p + lo1);
    }
  };

#define QUAD(AV, BV, MH, NQ)                                                   \
  do {                                                                         \
    _Pragma("unroll") for (int mi = 0; mi < 4; ++mi) {                         \
      _Pragma("unroll") for (int nj = 0; nj < 2; ++nj) {                       \
        acc[(MH)*4 + mi][(NQ)*2 + nj] =                                        \
            MFMA(AV[mi][0], BV[nj][0], acc[(MH)*4 + mi][(NQ)*2 + nj]);         \
        acc[(MH)*4 + mi][(NQ)*2 + nj] =                                        \
            MFMA(AV[mi][1], BV[nj][1], acc[(MH)*4 + mi][(NQ)*2 + nj]);         \
      }                                                                        \
    }                                                                          \
  } while (0)

  bf16x8 av[4][2], avh[4][2], bv0[2][2], bv1[2][2];

  // prologue: t0 all 4 half-tiles + B0(t1), A0(t1)
  STAGE(0, 0, 0, 0); STAGE(0, 0, 1, 0); STAGE(0, 1, 0, 0); STAGE(0, 1, 1, 0);
  STAGE(1, 1, 0, 1); STAGE(1, 0, 0, 1);
  asm volatile("s_waitcnt vmcnt(4)" ::: "memory");
  __builtin_amdgcn_sched_barrier(0);
  __builtin_amdgcn_s_barrier();

#pragma unroll 1
  for (int i = 0; i < NITER; ++i) {
    const int ta = 2 * i, tb = ta + 1;
    const bool st = (i + 1 < NITER);
    // M1: reads buf0 {A lo, B q0+q1}; stage A1(tb), B1(tb)
    LOAD_AV(av, 0, 0); LOAD_BV(bv0, 0, 0); LOAD_BV(bv1, 0, 1);
    STAGE(1, 0, 1, tb); STAGE(1, 1, 1, tb);
    PH_BAR();
    __builtin_amdgcn_s_setprio(1);
    QUAD(av, bv0, 0, 0); QUAD(av, bv1, 0, 1);
    __builtin_amdgcn_s_setprio(0);
    PH_END();
    // M2: reads buf0 {A hi}; stage B0(ta+2), A0(ta+2); vmcnt -> tb(A1,B1) landed
    LOAD_AV(avh, 0, 1);
    if (st) { STAGE(0, 1, 0, ta + 2); STAGE(0, 0, 0, ta + 2); }
    PH_BAR();
    __builtin_amdgcn_s_setprio(1);
    QUAD(avh, bv0, 1, 0); QUAD(avh, bv1, 1, 1);
    __builtin_amdgcn_s_setprio(0);
    if (st) asm volatile("s_waitcnt vmcnt(4)" ::: "memory");
    else    asm volatile("s_waitcnt vmcnt(0)" ::: "memory");
    PH_END();
    // M3: reads buf1 {A lo, B q0+q1}; stage A1(ta+2), B1(ta+2)
    LOAD_AV(av, 1, 0); LOAD_BV(bv0, 1, 0); LOAD_BV(bv1, 1, 1);
    if (st) { STAGE(0, 0, 1, ta + 2); STAGE(0, 1, 1, ta + 2); }
    PH_BAR();
    __builtin_amdgcn_s_setprio(1);
    QUAD(av, bv0, 0, 0); QUAD(av, bv1, 0, 1);
    __builtin_amdgcn_s_setprio(0);
    PH_END();
    // M4: reads buf1 {A hi}; stage B0(tb+2), A0(tb+2); vmcnt -> ta+2 fully landed
    LOAD_AV(avh, 1, 1);
    if (st) { STAGE(1, 1, 0, tb + 2); STAGE(1, 0, 0, tb + 2); }
    PH_BAR();
    __builtin_amdgcn_s_setprio(1);
    QUAD(avh, bv0, 1, 0); QUAD(avh, bv1, 1, 1);
    __builtin_amdgcn_s_setprio(0);
    if (st) asm volatile("s_waitcnt vmcnt(4)" ::: "memory");
    PH_END();
  }

#pragma unroll
  for (int MI = 0; MI < 8; ++MI) {
    const int row = m0 + wr * 128 + MI * 16 + (lane >> 4) * 4;
#pragma unroll
    for (int NJ = 0; NJ < 4; ++NJ) {
      const int col = bn0 + wc * 64 + NJ * 16 + (lane & 15);
      u16* p = (u16*)OutV + (size_t)row * N + col;
#pragma unroll
      for (int j = 0; j < 4; ++j) p[(size_t)j * N] = f2bf(acc[MI][NJ][j]);
    }
  }
}
#undef QUAD

// ============ GEMM2: weight-folded, A(h)-resident-in-registers ============
__global__ __launch_bounds__(512, 2) void gemm_fold(
    const u16* __restrict__ A,    // h  [8192][256] bf16
    const u16* __restrict__ Bn,   // Rt [16][1024][256] bf16
    const float* __restrict__ W,  // Wr [8192][16] f32
    float* __restrict__ Out) {    // [8192][1024] f32
  __shared__ u16 ldsB[8][8192];   // 128 KB: 4 pair-buffers of 2 half-tiles
  __shared__ u16 Wlds[16][264];   // bf16 weights, [n][row]

  const int tid = threadIdx.x;
  const int lane = tid & 63;
  const int wid = tid >> 6;
  const int kh = wid >> 2;
  const int wrM = (wid >> 1) & 1;
  const int wcN = wid & 1;

  // L2-aware chunked XCD swizzle: chunk = 2 bx x 16 by (Rt slice 2MB <= L2)
  // grid is 8 x 64 = 512 blocks
  const int L = blockIdx.y * gridDim.x + blockIdx.x;
  const int ordered = (L & 7) * 64 + (L >> 3);
  const int cid = ordered >> 5, win = ordered & 31;
  const int bx = (cid & 3) * 2 + (win & 1);
  const int by = (cid >> 2) * 16 + (win >> 1);
  const int m0 = by * 128, d0 = bx * 128;

  const int arow = lane & 15;
  const int acol = (lane >> 4) * 16;
  const int sw = (arow & 7) << 4;
  const int lo0 = arow * 128 + (acol ^ sw);
  const int lo1 = arow * 128 + ((64 + acol) ^ sw);

  for (int i = tid; i < 128 * 16; i += 512) {
    const int row = i >> 4, n = i & 15;
    Wlds[n][row] = f2bf(W[(size_t)(m0 + row) * 16 + n]);
  }

  auto ASTAGE = [&](int kt) {
    const u16* G = A + (size_t)m0 * 256;
    u16* Lp = &ldsB[kt][0];
#pragma unroll
    for (int j = 0; j < 2; ++j) {
      const int q = j * 8192 + tid * 16;
      const int grow = q >> 7;
      const int gcol = ((q & 127) ^ (((q >> 7) & 7) << 4)) >> 1;
      gload16(G + (size_t)grow * 256 + kt * 64 + gcol, Lp + ((j * 8192 + wid * 1024) >> 1));
    }
  };
  ASTAGE(0); ASTAGE(1); ASTAGE(2); ASTAGE(3);
  __syncthreads();
  bf16x8 avk[4][4];
#pragma unroll
  for (int c2 = 0; c2 < 2; ++c2) {
#pragma unroll
    for (int mi = 0; mi < 4; ++mi) {
      const char* p = (const char*)&ldsB[kh * 2 + c2][0] + (wrM * 64 + mi * 16) * 128;
      avk[c2 * 2 + 0][mi] = *(const bf16x8*)(p + lo0);
      avk[c2 * 2 + 1][mi] = *(const bf16x8*)(p + lo1);
    }
  }
  __syncthreads();

  auto BSTAGE = [&](int ss) {
    const int n = ss >> 1, h = ss & 1, p = ss & 3;
    const u16* G = Bn + ((size_t)n * 1024 + d0) * 256;
#pragma unroll
    for (int t = 0; t < 2; ++t) {
      u16* Lp = &ldsB[2 * p + t][0];
      const int kt = h + 2 * t;
#pragma unroll
      for (int j = 0; j < 2; ++j) {
        const int q = j * 8192 + tid * 16;
        const int grow = q >> 7;
        const int gcol = ((q & 127) ^ (((q >> 7) & 7) << 4)) >> 1;
        gload16(G + (size_t)grow * 256 + kt * 64 + gcol, Lp + ((j * 8192 + wid * 1024) >> 1));
      }
    }
  };

  f32x4 acc_t[4][4], acc_g[4][4];
#pragma unroll
  for (int mi = 0; mi < 4; ++mi)
#pragma unroll
    for (int nj = 0; nj < 4; ++nj) {
      acc_t[mi][nj] = (f32x4){0.f, 0.f, 0.f, 0.f};
      acc_g[mi][nj] = (f32x4){0.f, 0.f, 0.f, 0.f};
    }
  bf16x8 bv[4][2];

  BSTAGE(0); BSTAGE(1); BSTAGE(2);
  asm volatile("s_waitcnt vmcnt(8)" ::: "memory");
  __builtin_amdgcn_sched_barrier(0);
  __builtin_amdgcn_s_barrier();

  auto SSTEP = [&](int ss, int h, bool do_stage, int vmsel) {
    const int p = ss & 3;
    const char* pB = (const char*)&ldsB[2 * p + kh][0];
#pragma unroll
    for (int nj = 0; nj < 4; ++nj) {
      const char* q = pB + (wcN * 64 + nj * 16) * 128;
      bv[nj][0] = *(const bf16x8*)(q + lo0);
      bv[nj][1] = *(const bf16x8*)(q + lo1);
    }
    if (do_stage) BSTAGE(ss + 3);
    PH_BAR();
    __builtin_amdgcn_s_setprio(1);
#pragma unroll
    for (int mi = 0; mi < 4; ++mi)
#pragma unroll
      for (int nj = 0; nj < 4; ++nj) {
        acc_g[mi][nj] = MFMA(avk[2 * h + 0][mi], bv[nj][0], acc_g[mi][nj]);
        acc_g[mi][nj] = MFMA(avk[2 * h + 1][mi], bv[nj][1], acc_g[mi][nj]);
      }
    __builtin_amdgcn_s_setprio(0);
    if (vmsel == 8)      asm volatile("s_waitcnt vmcnt(8)" ::: "memory");
    else if (vmsel == 4) asm volatile("s_waitcnt vmcnt(4)" ::: "memory");
    else if (vmsel == 0) asm volatile("s_waitcnt vmcnt(0)" ::: "memory");
    PH_END();
  };
  auto FOLD = [&](int n) {
#pragma unroll
    for (int mi = 0; mi < 4; ++mi) {
      const int rbase = wrM * 64 + mi * 16 + (lane >> 4) * 4;
      u16x4 wq = *(const u16x4*)&Wlds[n][rbase];
      const float w0 = bf2f(wq[0]), w1 = bf2f(wq[1]), w2 = bf2f(wq[2]), w3 = bf2f(wq[3]);
#pragma unroll
      for (int nj = 0; nj < 4; ++nj) {
        acc_t[mi][nj][0] += w0 * acc_g[mi][nj][0];
        acc_t[mi][nj][1] += w1 * acc_g[mi][nj][1];
        acc_t[mi][nj][2] += w2 * acc_g[mi][nj][2];
        acc_t[mi][nj][3] += w3 * acc_g[mi][nj][3];
        acc_g[mi][nj] = (f32x4){0.f, 0.f, 0.f, 0.f};
      }
    }
  };

#pragma unroll 1
  for (int nn = 0; nn < 14; ++nn) {
    SSTEP(nn * 2 + 0, 0, true, 8);
    SSTEP(nn * 2 + 1, 1, true, 8);
    FOLD(nn);
  }
  SSTEP(28, 0, true, 8);
  SSTEP(29, 1, false, 4);
  FOLD(14);
  SSTEP(30, 0, false, 0);
  SSTEP(31, 1, false, -1);
  FOLD(15);

  __syncthreads();
  float* red = (float*)&ldsB[0][0];
  const int reg = (wrM * 2 + wcN) * 4096;
  if (kh == 1) {
#pragma unroll
    for (int mi = 0; mi < 4; ++mi)
#pragma unroll
      for (int j = 0; j < 4; ++j) {
        const int r = mi * 16 + (lane >> 4) * 4 + j;
#pragma unroll
        for (int nj = 0; nj < 4; ++nj)
          red[reg + r * 64 + nj * 16 + (lane & 15)] = acc_t[mi][nj][j];
      }
  }
  __syncthreads();
  if (kh == 0) {
#pragma unroll
    for (int mi = 0; mi < 4; ++mi) {
      const int rr = mi * 16 + (lane >> 4) * 4;
#pragma unroll
      for (int j = 0; j < 4; ++j) {
        float* orow = Out + (size_t)(m0 + wrM * 64 + rr + j) * 1024 + d0 + wcN * 64 + (lane & 15);
#pragma unroll
        for (int nj = 0; nj < 4; ++nj)
          orow[nj * 16] = acc_t[mi][nj][j] + red[reg + (rr + j) * 64 + nj * 16 + (lane & 15)];
      }
    }
  }
}

extern "C" void kernel_launch(void* const* d_in, const int* in_sizes, int n_in,
                              void* d_out, int out_size, void* d_ws, size_t ws_size,
                              hipStream_t stream) {
  const float* x  = (const float*)d_in[0];   // [8192][1024]
  const float* F  = (const float*)d_in[1];   // [16][1024][256]
  const float* Rk = (const float*)d_in[2];   // [16][256][1024]
  const float* Wf = (const float*)d_in[3];   // [8192][16]
  const float* Wr = (const float*)d_in[4];   // [8192][16]
  float* out = (float*)d_out;                // [8192][1024]

  char* ws = (char*)d_ws;
  u16* X16 = (u16*)(ws);                 // 16 MB  x bf16 [8192][1024]
  u16* B1  = (u16*)(ws + (16u << 20));   //  8 MB  F^T  [(n,r)=4096][1024]
  u16* Rt  = (u16*)(ws + (24u << 20));   //  8 MB  Rk^T [16][1024][256]
  u16* T   = (u16*)(ws + (32u << 20));   // 64 MB  T bf16 [8192][4096]
  u16* h16 = (u16*)(ws);                 //  4 MB  h bf16 [8192][256] (reuses X16)

  cast_x_kernel<<<2048, 256, 0, stream>>>(x, X16, (M_TOK * 1024) / 4);
  tcast_kernel<<<dim3(8, 32, 16), 256, 0, stream>>>(F, B1, 1024, 256);
  tcast_kernel<<<dim3(32, 8, 16), 256, 0, stream>>>(Rk, Rt, 256, 1024);

  gemm256<16><<<dim3(16, 32, 1), 512, 0, stream>>>(X16, B1, T, 4096, 1024);
  combine_h<<<2048, 256, 0, stream>>>(T, Wf, h16);
  gemm_fold<<<dim3(8, 64, 1), 512, 0, stream>>>(h16, Rt, Wr, out);
}